// Round 1
// baseline (3630.112 us; speedup 1.0000x reference)
//
#include <hip/hip_runtime.h>
#include <hip/hip_bf16.h>
#include <math.h>

// Problem constants
#define BB 64
#define SS 256
#define DD 1024
#define HH 16
#define FFN 4096
#define GHH 100
#define NCC 7
#define LL 4
#define TT (BB*SS)          // 16384 tokens
#define DHH 64

typedef unsigned short u16;
typedef unsigned int u32;
typedef __attribute__((ext_vector_type(4))) float f32x4;
typedef __attribute__((ext_vector_type(8))) short s16x8;
typedef __attribute__((ext_vector_type(4))) unsigned short u16x4;

__device__ __forceinline__ u16 f2bf(float f) {
  union { float f; u32 u; } x; x.f = f;
  u32 r = x.u + 0x7FFFu + ((x.u >> 16) & 1u);
  return (u16)(r >> 16);
}

__device__ __forceinline__ void load_lds16(const u16* g, u16* l) {
  __builtin_amdgcn_global_load_lds(
      (const __attribute__((address_space(1))) u32*)g,
      (__attribute__((address_space(3))) u32*)l, 16, 0, 0);
}

// ---------------- fp32 -> bf16 convert ----------------
__global__ void k_f2bf(const float* __restrict__ in, u16* __restrict__ out, int n4) {
  int stride = gridDim.x * blockDim.x;
  for (int i = blockIdx.x * blockDim.x + threadIdx.x; i < n4; i += stride) {
    f32x4 v = *(const f32x4*)(in + (size_t)i * 4);
    u16x4 o;
    o[0] = f2bf(v[0]); o[1] = f2bf(v[1]); o[2] = f2bf(v[2]); o[3] = f2bf(v[3]);
    *(u16x4*)(out + (size_t)i * 4) = o;
  }
}

// ---------------- positional encoding ----------------
__global__ void k_pe(float* __restrict__ pe) {
  int i = blockIdx.x * blockDim.x + threadIdx.x;     // over S*D/2
  if (i >= SS * DD / 2) return;
  int s = i / (DD / 2), j = i % (DD / 2);
  float div = __expf((float)(2 * j) * (-9.210340371976184f / (float)DD));
  float a = (float)s * div;
  pe[s * DD + 2 * j]     = sinf(a);
  pe[s * DD + 2 * j + 1] = cosf(a);
}

// ---------------- embedding + PE ----------------
__global__ void k_embed(const int* __restrict__ src, const float* __restrict__ emb,
                        const float* __restrict__ pe, float* __restrict__ x32,
                        u16* __restrict__ xb) {
  int i = blockIdx.x * blockDim.x + threadIdx.x;     // over T*D/4
  if (i >= TT * DD / 4) return;
  int t = i / (DD / 4);
  int d4 = (i % (DD / 4)) * 4;
  int s = t % SS;
  int tok = src[t];
  f32x4 e = *(const f32x4*)(emb + (size_t)tok * DD + d4);
  f32x4 p = *(const f32x4*)(pe + (size_t)s * DD + d4);
  f32x4 r;
  r[0] = e[0] * 32.0f + p[0]; r[1] = e[1] * 32.0f + p[1];
  r[2] = e[2] * 32.0f + p[2]; r[3] = e[3] * 32.0f + p[3];
  *(f32x4*)(x32 + (size_t)t * DD + d4) = r;
  u16x4 o;
  o[0] = f2bf(r[0]); o[1] = f2bf(r[1]); o[2] = f2bf(r[2]); o[3] = f2bf(r[3]);
  *(u16x4*)(xb + (size_t)t * DD + d4) = o;
}

// ---------------- GEMM: C = A(bf16,MxK) @ W(bf16,NxK)^T + bias ----------------
// EPI: 0 = bf16 out, 1 = relu + bf16 out, 2 = f32 out
template<int EPI>
__global__ __launch_bounds__(256)
void k_gemm(const u16* __restrict__ A, const u16* __restrict__ W,
            const float* __restrict__ bias, void* __restrict__ Cout,
            int M, int N, int K) {
  __shared__ u16 As[128 * 64];
  __shared__ u16 Bs[128 * 64];
  const int lane = threadIdx.x & 63;
  const int wave = threadIdx.x >> 6;
  const int n0 = blockIdx.x * 128;
  const int m0 = blockIdx.y * 128;
  const int wm = wave >> 1, wn = wave & 1;
  const int rA = lane >> 3;
  const int c8 = (lane & 7) * 8;
  const int lm = lane & 15, lg = lane >> 4;

  f32x4 zero = {0.f, 0.f, 0.f, 0.f};
  f32x4 acc[4][4];
#pragma unroll
  for (int i = 0; i < 4; i++)
#pragma unroll
    for (int j = 0; j < 4; j++) acc[i][j] = zero;

  for (int kt = 0; kt < K; kt += 64) {
#pragma unroll
    for (int i = 0; i < 4; ++i) {
      int ch = wave * 4 + i;
      int row = ch * 8 + rA;
      load_lds16(A + (size_t)(m0 + row) * K + kt + c8, &As[ch * 512]);
      load_lds16(W + (size_t)(n0 + row) * K + kt + c8, &Bs[ch * 512]);
    }
    __syncthreads();
#pragma unroll
    for (int kk = 0; kk < 2; ++kk) {
      s16x8 af[4], bfr[4];
#pragma unroll
      for (int i = 0; i < 4; i++)
        af[i] = *(const s16x8*)&As[(wm * 64 + i * 16 + lm) * 64 + kk * 32 + lg * 8];
#pragma unroll
      for (int j = 0; j < 4; j++)
        bfr[j] = *(const s16x8*)&Bs[(wn * 64 + j * 16 + lm) * 64 + kk * 32 + lg * 8];
#pragma unroll
      for (int i = 0; i < 4; i++)
#pragma unroll
        for (int j = 0; j < 4; j++)
          acc[i][j] = __builtin_amdgcn_mfma_f32_16x16x32_bf16(af[i], bfr[j], acc[i][j], 0, 0, 0);
    }
    __syncthreads();
  }

  float bn[4];
#pragma unroll
  for (int j = 0; j < 4; j++) bn[j] = bias[n0 + wn * 64 + j * 16 + lm];
#pragma unroll
  for (int i = 0; i < 4; i++) {
#pragma unroll
    for (int j = 0; j < 4; j++) {
      int col = n0 + wn * 64 + j * 16 + lm;
#pragma unroll
      for (int r = 0; r < 4; r++) {
        int row = m0 + wm * 64 + i * 16 + lg * 4 + r;
        float v = acc[i][j][r] + bn[j];
        if (EPI == 1) v = fmaxf(v, 0.f);
        if (EPI <= 1) ((u16*)Cout)[(size_t)row * N + col] = f2bf(v);
        else          ((float*)Cout)[(size_t)row * N + col] = v;
      }
    }
  }
}

// ---------------- fused causal attention ----------------
__global__ __launch_bounds__(256)
void k_attn(const u16* __restrict__ qkv, u16* __restrict__ o) {
  const int qb = blockIdx.x;    // 0..3
  const int h  = blockIdx.y;    // 0..15
  const int b  = blockIdx.z;    // 0..63
  const int lane = threadIdx.x & 63;
  const int wave = threadIdx.x >> 6;
  const int lm = lane & 15, lg = lane >> 4;

  __shared__ u16 Ks[64 * 64];      // [k_local][dh]
  __shared__ u16 Vt[64 * 64];      // [dh][k_local]
  __shared__ u16 Ps[4][16 * 64];   // per-wave P [qr][k_local]

  const int q0 = qb * 64 + wave * 16;
  const size_t tokbase = (size_t)b * SS;

  // Q fragments in registers (rows q0+lm, dh 8-contig)
  s16x8 aq[2];
  {
    const u16* qrow = qkv + (tokbase + q0 + lm) * 3072 + h * 64;
    aq[0] = *(const s16x8*)(qrow + lg * 8);
    aq[1] = *(const s16x8*)(qrow + 32 + lg * 8);
  }

  f32x4 zero = {0.f, 0.f, 0.f, 0.f};
  f32x4 oacc[4];
#pragma unroll
  for (int j = 0; j < 4; j++) oacc[j] = zero;
  float m_run[4], l_run[4];
#pragma unroll
  for (int r = 0; r < 4; r++) { m_run[r] = -3e38f; l_run[r] = 0.f; }

  const int nkb = qb + 1;
  for (int kb = 0; kb < nkb; ++kb) {
    __syncthreads();
    // stage K block + V^T block
    {
      int krow = threadIdx.x >> 2;
      int seg  = (threadIdx.x & 3) * 16;
      const u16* ksrc = qkv + (tokbase + kb * 64 + krow) * 3072 + 1024 + h * 64 + seg;
      s16x8 v0 = *(const s16x8*)(ksrc);
      s16x8 v1 = *(const s16x8*)(ksrc + 8);
      *(s16x8*)&Ks[krow * 64 + seg] = v0;
      *(s16x8*)&Ks[krow * 64 + seg + 8] = v1;
      const u16* vsrc = qkv + (tokbase + kb * 64 + krow) * 3072 + 2048 + h * 64 + seg;
      s16x8 w0 = *(const s16x8*)(vsrc);
      s16x8 w1 = *(const s16x8*)(vsrc + 8);
#pragma unroll
      for (int e = 0; e < 8; e++) {
        Vt[(seg + e) * 64 + krow]     = (u16)w0[e];
        Vt[(seg + 8 + e) * 64 + krow] = (u16)w1[e];
      }
    }
    __syncthreads();

    // S = Q K^T
    f32x4 sfr[4];
#pragma unroll
    for (int j = 0; j < 4; j++) {
      f32x4 acc = zero;
#pragma unroll
      for (int kk = 0; kk < 2; kk++) {
        s16x8 bk = *(const s16x8*)&Ks[(j * 16 + lm) * 64 + kk * 32 + lg * 8];
        acc = __builtin_amdgcn_mfma_f32_16x16x32_bf16(aq[kk], bk, acc, 0, 0, 0);
      }
      sfr[j] = acc;
    }
    // scale + causal mask
    const int colbase = kb * 64;
#pragma unroll
    for (int j = 0; j < 4; j++) {
      int col = colbase + j * 16 + lm;
#pragma unroll
      for (int r = 0; r < 4; r++) {
        int row = q0 + lg * 4 + r;
        float v = sfr[j][r] * 0.125f;
        sfr[j][r] = (col <= row) ? v : -1e30f;
      }
    }
    // online softmax
    float mb[4];
#pragma unroll
    for (int r = 0; r < 4; r++) {
      float m = fmaxf(fmaxf(sfr[0][r], sfr[1][r]), fmaxf(sfr[2][r], sfr[3][r]));
#pragma unroll
      for (int off = 1; off < 16; off <<= 1) m = fmaxf(m, __shfl_xor(m, off));
      mb[r] = m;
    }
    float fo[4];
#pragma unroll
    for (int r = 0; r < 4; r++) {
      float mnew = fmaxf(m_run[r], mb[r]);
      fo[r] = __expf(m_run[r] - mnew);
      m_run[r] = mnew;
    }
    float ps[4] = {0.f, 0.f, 0.f, 0.f};
#pragma unroll
    for (int j = 0; j < 4; j++)
#pragma unroll
      for (int r = 0; r < 4; r++) {
        float p = __expf(sfr[j][r] - m_run[r]);
        sfr[j][r] = p;
        ps[r] += p;
      }
#pragma unroll
    for (int r = 0; r < 4; r++) {
#pragma unroll
      for (int off = 1; off < 16; off <<= 1) ps[r] += __shfl_xor(ps[r], off);
      l_run[r] = l_run[r] * fo[r] + ps[r];
    }
#pragma unroll
    for (int j = 0; j < 4; j++)
#pragma unroll
      for (int r = 0; r < 4; r++) oacc[j][r] *= fo[r];
    // P -> LDS (wave-private)
#pragma unroll
    for (int j = 0; j < 4; j++)
#pragma unroll
      for (int r = 0; r < 4; r++)
        Ps[wave][(lg * 4 + r) * 64 + j * 16 + lm] = f2bf(sfr[j][r]);
    asm volatile("" ::: "memory");
    // O += P V
#pragma unroll
    for (int kk = 0; kk < 2; kk++) {
      s16x8 pa = *(const s16x8*)&Ps[wave][lm * 64 + kk * 32 + lg * 8];
#pragma unroll
      for (int j2 = 0; j2 < 4; j2++) {
        s16x8 bv = *(const s16x8*)&Vt[(j2 * 16 + lm) * 64 + kk * 32 + lg * 8];
        oacc[j2] = __builtin_amdgcn_mfma_f32_16x16x32_bf16(pa, bv, oacc[j2], 0, 0, 0);
      }
    }
  }
  // normalize + store
#pragma unroll
  for (int j2 = 0; j2 < 4; j2++)
#pragma unroll
    for (int r = 0; r < 4; r++) {
      int row = q0 + lg * 4 + r;
      float val = oacc[j2][r] / l_run[r];
      o[(tokbase + row) * 1024 + h * 64 + j2 * 16 + lm] = f2bf(val);
    }
}

// ---------------- residual + LayerNorm ----------------
__global__ __launch_bounds__(256)
void k_ln(const float* __restrict__ xin, const float* __restrict__ tmp,
          const float* __restrict__ gam, const float* __restrict__ bet,
          float* __restrict__ xout, u16* __restrict__ xb) {
  int t = blockIdx.x;
  int tid = threadIdx.x;
  f32x4 v = *(const f32x4*)(xin + (size_t)t * DD + tid * 4);
  f32x4 u = *(const f32x4*)(tmp + (size_t)t * DD + tid * 4);
  v[0] += u[0]; v[1] += u[1]; v[2] += u[2]; v[3] += u[3];
  float s = v[0] + v[1] + v[2] + v[3];
  float s2 = v[0]*v[0] + v[1]*v[1] + v[2]*v[2] + v[3]*v[3];
#pragma unroll
  for (int off = 32; off >= 1; off >>= 1) {
    s  += __shfl_xor(s, off);
    s2 += __shfl_xor(s2, off);
  }
  __shared__ float red[8];
  int w = tid >> 6;
  if ((tid & 63) == 0) { red[w] = s; red[4 + w] = s2; }
  __syncthreads();
  s  = red[0] + red[1] + red[2] + red[3];
  s2 = red[4] + red[5] + red[6] + red[7];
  float mean = s * (1.f / 1024.f);
  float var = s2 * (1.f / 1024.f) - mean * mean;
  float rstd = rsqrtf(var + 1e-5f);
  f32x4 g4 = *(const f32x4*)(gam + tid * 4);
  f32x4 b4 = *(const f32x4*)(bet + tid * 4);
  f32x4 y;
  u16x4 yo;
#pragma unroll
  for (int e = 0; e < 4; e++) {
    y[e] = (v[e] - mean) * rstd * g4[e] + b4[e];
    yo[e] = f2bf(y[e]);
  }
  *(f32x4*)(xout + (size_t)t * DD + tid * 4) = y;
  *(u16x4*)(xb + (size_t)t * DD + tid * 4) = yo;
}

// ---------------- GRU input projection: xp[s][b][g] ----------------
__global__ void k_gruxp(const float* __restrict__ em, const float* __restrict__ Wih,
                        const float* __restrict__ bih, float* __restrict__ xp) {
  int i = blockIdx.x * blockDim.x + threadIdx.x;   // over S*B*300
  if (i >= SS * BB * 300) return;
  int g = i % 300;
  int sb = i / 300;
  int b = sb % BB;
  int s = sb / BB;
  const float* e = em + ((size_t)b * SS + s) * 7;
  const float* w = Wih + (size_t)g * 7;
  float acc = bih[g];
#pragma unroll
  for (int f = 0; f < 7; f++) acc += e[f] * w[f];
  xp[i] = acc;
}

// ---------------- GRU sequential scan ----------------
__global__ __launch_bounds__(320)
void k_gru(const float* __restrict__ xp, const float* __restrict__ Whh,
           const float* __restrict__ bhh, float* __restrict__ emo) {
  const int b = blockIdx.x;
  const int j = threadIdx.x;
  __shared__ float h[100];
  __shared__ float hp[304];
  float wreg[100];
  if (j < 300) {
#pragma unroll
    for (int k = 0; k < 100; k++) wreg[k] = Whh[(size_t)j * 100 + k];
  }
  float bj = (j < 300) ? bhh[j] : 0.f;
  if (j < 100) h[j] = 0.f;
  __syncthreads();
  for (int s = 0; s < SS; ++s) {
    const float* xr = xp + ((size_t)s * BB + b) * 300;
    float x0 = 0.f, x1 = 0.f, x2 = 0.f;
    if (j < 100) { x0 = xr[j]; x1 = xr[100 + j]; x2 = xr[200 + j]; }
    if (j < 300) {
      float acc = bj;
#pragma unroll
      for (int k = 0; k < 100; k++) acc += wreg[k] * h[k];
      hp[j] = acc;
    }
    __syncthreads();
    if (j < 100) {
      float r = 1.f / (1.f + expf(-(x0 + hp[j])));
      float z = 1.f / (1.f + expf(-(x1 + hp[100 + j])));
      float n = tanhf(x2 + r * hp[200 + j]);
      float hn = (1.f - z) * n + z * h[j];
      h[j] = hn;
      emo[((size_t)b * SS + s) * 100 + j] = hn;
    }
    __syncthreads();
  }
}

// ---------------- main-token dot precompute ----------------
__global__ void k_main(const int* __restrict__ d_ids, const int* __restrict__ ut_len,
                       const float* __restrict__ x32, const float* __restrict__ decW,
                       float* __restrict__ md) {
  int b = blockIdx.x;
  int lane = threadIdx.x;   // 64
  int len = ut_len[d_ids[b]];
  const float* xr = x32 + ((size_t)b * SS + (len - 1)) * DD;
  float acc[NCC];
#pragma unroll
  for (int c = 0; c < NCC; c++) acc[c] = 0.f;
  for (int d = lane; d < DD; d += 64) {
    float xv = xr[d];
#pragma unroll
    for (int c = 0; c < NCC; c++) acc[c] += xv * decW[(size_t)c * 2148 + 1024 + d];
  }
#pragma unroll
  for (int c = 0; c < NCC; c++) {
#pragma unroll
    for (int off = 32; off >= 1; off >>= 1) acc[c] += __shfl_xor(acc[c], off);
  }
  if (lane == 0) {
#pragma unroll
    for (int c = 0; c < NCC; c++) md[b * NCC + c] = acc[c];
  }
}

// ---------------- decoder ----------------
__global__ __launch_bounds__(256)
void k_dec(const float* __restrict__ x32, const float* __restrict__ emo,
           const float* __restrict__ md, const float* __restrict__ decW,
           const float* __restrict__ decb, const int* __restrict__ d_ids,
           const int* __restrict__ ut_len, float* __restrict__ out) {
  int grp = threadIdx.x >> 6, lane = threadIdx.x & 63;
  int t = blockIdx.x * 4 + grp;
  int b = t / SS, s = t % SS;
  int len = ut_len[d_ids[b]];
  bool valid = s < len;
  float acc[NCC];
#pragma unroll
  for (int c = 0; c < NCC; c++) acc[c] = 0.f;
  if (valid) {
    const float* xr = x32 + (size_t)t * DD;
    for (int d = lane; d < DD; d += 64) {
      float xv = xr[d];
#pragma unroll
      for (int c = 0; c < NCC; c++) acc[c] += xv * decW[(size_t)c * 2148 + d];
    }
  }
  {
    const float* er = emo + (size_t)t * GHH;
    for (int d = lane; d < GHH; d += 64) {
      float ev = er[d];
#pragma unroll
      for (int c = 0; c < NCC; c++) acc[c] += ev * decW[(size_t)c * 2148 + 2048 + d];
    }
  }
#pragma unroll
  for (int c = 0; c < NCC; c++) {
#pragma unroll
    for (int off = 32; off >= 1; off >>= 1) acc[c] += __shfl_xor(acc[c], off);
  }
  if (lane == 0) {
#pragma unroll
    for (int c = 0; c < NCC; c++) {
      float v = acc[c] + (valid ? md[b * NCC + c] : 0.f) + decb[c];
      out[(size_t)t * NCC + c] = v;
    }
  }
}

// ---------------- launch ----------------
extern "C" void kernel_launch(void* const* d_in, const int* in_sizes, int n_in,
                              void* d_out, int out_size, void* d_ws, size_t ws_size,
                              hipStream_t stream) {
  const int*   src    = (const int*)d_in[0];
  const float* em_seq = (const float*)d_in[1];
  const int*   d_ids  = (const int*)d_in[2];
  const int*   ut_len = (const int*)d_in[3];
  const float* emb    = (const float*)d_in[4];
  const float* Wqkv   = (const float*)d_in[5];
  const float* bqkv   = (const float*)d_in[6];
  const float* Wo     = (const float*)d_in[7];
  const float* bo     = (const float*)d_in[8];
  const float* W1     = (const float*)d_in[9];
  const float* b1     = (const float*)d_in[10];
  const float* W2     = (const float*)d_in[11];
  const float* b2     = (const float*)d_in[12];
  const float* ln1g   = (const float*)d_in[13];
  const float* ln1b   = (const float*)d_in[14];
  const float* ln2g   = (const float*)d_in[15];
  const float* ln2b   = (const float*)d_in[16];
  const float* gWih   = (const float*)d_in[17];
  const float* gWhh   = (const float*)d_in[18];
  const float* gbih   = (const float*)d_in[19];
  const float* gbhh   = (const float*)d_in[20];
  const float* decW   = (const float*)d_in[21];
  const float* decb   = (const float*)d_in[22];
  float* out = (float*)d_out;

  char* wsp = (char*)d_ws;
  auto take = [&](size_t n) { char* p = wsp; wsp += (n + 255) & ~(size_t)255; return p; };

  u16*   wqkvb = (u16*)take((size_t)3072 * 1024 * 2);
  u16*   wob   = (u16*)take((size_t)1024 * 1024 * 2);
  u16*   w1b   = (u16*)take((size_t)4096 * 1024 * 2);
  u16*   w2b   = (u16*)take((size_t)1024 * 4096 * 2);
  float* pe    = (float*)take((size_t)SS * DD * 4);
  float* x32   = (float*)take((size_t)TT * DD * 4);
  u16*   xb    = (u16*)take((size_t)TT * DD * 2);
  u16*   big   = (u16*)take((size_t)TT * FFN * 2);   // qkv (T x 3072) or ff1 (T x 4096)
  u16*   ob    = (u16*)take((size_t)TT * DD * 2);
  float* tmp32 = (float*)take((size_t)TT * DD * 4);
  float* xp    = (float*)take((size_t)SS * BB * 300 * 4);
  float* emo   = (float*)take((size_t)BB * SS * GHH * 4);
  float* md    = (float*)take((size_t)BB * NCC * 4);

  // GRU path (independent of transformer)
  k_gruxp<<<(SS * BB * 300 + 255) / 256, 256, 0, stream>>>(em_seq, gWih, gbih, xp);
  k_gru<<<BB, 320, 0, stream>>>(xp, gWhh, gbhh, emo);

  // embedding + positional encoding
  k_pe<<<(SS * DD / 2 + 255) / 256, 256, 0, stream>>>(pe);
  k_embed<<<TT * DD / 4 / 256, 256, 0, stream>>>(src, emb, pe, x32, xb);

  for (int l = 0; l < LL; ++l) {
    // convert this layer's weights to bf16
    k_f2bf<<<2048, 256, 0, stream>>>(Wqkv + (size_t)l * 3072 * 1024, wqkvb, 3072 * 1024 / 4);
    k_f2bf<<<2048, 256, 0, stream>>>(Wo   + (size_t)l * 1024 * 1024, wob,   1024 * 1024 / 4);
    k_f2bf<<<2048, 256, 0, stream>>>(W1   + (size_t)l * 4096 * 1024, w1b,   4096 * 1024 / 4);
    k_f2bf<<<2048, 256, 0, stream>>>(W2   + (size_t)l * 1024 * 4096, w2b,   1024 * 4096 / 4);

    // QKV projection
    k_gemm<0><<<dim3(3072 / 128, TT / 128), 256, 0, stream>>>(
        xb, wqkvb, bqkv + (size_t)l * 3072, big, TT, 3072, 1024);
    // attention
    k_attn<<<dim3(4, HH, BB), 256, 0, stream>>>(big, ob);
    // output projection (f32 out)
    k_gemm<2><<<dim3(1024 / 128, TT / 128), 256, 0, stream>>>(
        ob, wob, bo + (size_t)l * 1024, tmp32, TT, 1024, 1024);
    // residual + LN1
    k_ln<<<TT, 256, 0, stream>>>(x32, tmp32, ln1g + (size_t)l * DD, ln1b + (size_t)l * DD, x32, xb);
    // FFN1 (relu, bf16 out)
    k_gemm<1><<<dim3(4096 / 128, TT / 128), 256, 0, stream>>>(
        xb, w1b, b1 + (size_t)l * 4096, big, TT, 4096, 1024);
    // FFN2 (f32 out)
    k_gemm<2><<<dim3(1024 / 128, TT / 128), 256, 0, stream>>>(
        big, w2b, b2 + (size_t)l * 1024, tmp32, TT, 1024, 4096);
    // residual + LN2
    k_ln<<<TT, 256, 0, stream>>>(x32, tmp32, ln2g + (size_t)l * DD, ln2b + (size_t)l * DD, x32, xb);
  }

  // decoder
  k_main<<<BB, 64, 0, stream>>>(d_ids, ut_len, x32, decW, md);
  k_dec<<<TT / 4, 256, 0, stream>>>(x32, emo, md, decW, decb, d_ids, ut_len, out);
}

// Round 2
// 2656.960 us; speedup vs baseline: 1.3663x; 1.3663x over previous
//
#include <hip/hip_runtime.h>
#include <hip/hip_bf16.h>
#include <math.h>

// Problem constants
#define BB 64
#define SS 256
#define DD 1024
#define HH 16
#define FFN 4096
#define GHH 100
#define NCC 7
#define LL 4
#define TT (BB*SS)          // 16384 tokens
#define DHH 64

typedef unsigned short u16;
typedef unsigned int u32;
typedef __attribute__((ext_vector_type(4))) float f32x4;
typedef __attribute__((ext_vector_type(8))) short s16x8;
typedef __attribute__((ext_vector_type(4))) unsigned short u16x4;

__device__ __forceinline__ u16 f2bf(float f) {
  union { float f; u32 u; } x; x.f = f;
  u32 r = x.u + 0x7FFFu + ((x.u >> 16) & 1u);
  return (u16)(r >> 16);
}
__device__ __forceinline__ float bf2f(u16 b) {
  union { u32 u; float f; } x; x.u = ((u32)b) << 16;
  return x.f;
}

// ---------------- fp32 -> bf16 convert ----------------
__global__ void k_f2bf(const float* __restrict__ in, u16* __restrict__ out, int n4) {
  int stride = gridDim.x * blockDim.x;
  for (int i = blockIdx.x * blockDim.x + threadIdx.x; i < n4; i += stride) {
    f32x4 v = *(const f32x4*)(in + (size_t)i * 4);
    u16x4 o;
    o[0] = f2bf(v[0]); o[1] = f2bf(v[1]); o[2] = f2bf(v[2]); o[3] = f2bf(v[3]);
    *(u16x4*)(out + (size_t)i * 4) = o;
  }
}

// ---------------- positional encoding ----------------
__global__ void k_pe(float* __restrict__ pe) {
  int i = blockIdx.x * blockDim.x + threadIdx.x;     // over S*D/2
  if (i >= SS * DD / 2) return;
  int s = i / (DD / 2), j = i % (DD / 2);
  float div = __expf((float)(2 * j) * (-9.210340371976184f / (float)DD));
  float a = (float)s * div;
  pe[s * DD + 2 * j]     = sinf(a);
  pe[s * DD + 2 * j + 1] = cosf(a);
}

// ---------------- embedding + PE ----------------
__global__ void k_embed(const int* __restrict__ src, const float* __restrict__ emb,
                        const float* __restrict__ pe, float* __restrict__ x32,
                        u16* __restrict__ xb) {
  int i = blockIdx.x * blockDim.x + threadIdx.x;     // over T*D/4
  if (i >= TT * DD / 4) return;
  int t = i / (DD / 4);
  int d4 = (i % (DD / 4)) * 4;
  int s = t % SS;
  int tok = src[t];
  f32x4 e = *(const f32x4*)(emb + (size_t)tok * DD + d4);
  f32x4 p = *(const f32x4*)(pe + (size_t)s * DD + d4);
  f32x4 r;
  r[0] = e[0] * 32.0f + p[0]; r[1] = e[1] * 32.0f + p[1];
  r[2] = e[2] * 32.0f + p[2]; r[3] = e[3] * 32.0f + p[3];
  *(f32x4*)(x32 + (size_t)t * DD + d4) = r;
  u16x4 o;
  o[0] = f2bf(r[0]); o[1] = f2bf(r[1]); o[2] = f2bf(r[2]); o[3] = f2bf(r[3]);
  *(u16x4*)(xb + (size_t)t * DD + d4) = o;
}

// ---------------- 256x256 8-phase GEMM (T1+T2+T3+T4+T5) ----------------
// C(bf16) = A(bf16, MxK) @ W(bf16, NxK)^T + bias ; EPI: 0 plain, 1 relu
// 512 thr = 8 waves (2M x 4N); per-wave 128x64 out; BK=64; LDS 128KiB dbuf.
// Swizzle st_16x32: byte ^= ((byte>>9)&1)<<5 applied to (pre-swizzled) global
// source + swizzled ds_read address; LDS dest of global_load_lds stays linear.

#define MEMF asm volatile("" ::: "memory")
#define GBAR do { MEMF; __builtin_amdgcn_sched_barrier(0); __builtin_amdgcn_s_barrier(); __builtin_amdgcn_sched_barrier(0); MEMF; } while(0)
#define VMW4 asm volatile("s_waitcnt vmcnt(4)" ::: "memory")

#define STG(P, isB, h, l, buf, kt) \
  __builtin_amdgcn_global_load_lds( \
    (const __attribute__((address_space(1))) u32*)(P[h][l] + (kt)), \
    (__attribute__((address_space(3))) u32*)(smem + (buf)*65536 + (isB)*32768 + (h)*16384 + (l)*8192 + wid*1024), \
    16, 0, 0)

#define LDB(buf) do { \
  _Pragma("unroll") for (int nf = 0; nf < 4; nf++) \
  _Pragma("unroll") for (int kk = 0; kk < 2; kk++) { \
    int rel = (wn*64 + nf*16 + lm)*128 + kk*64 + lg*16; \
    bq[nf][kk] = *(const s16x8*)(smem + (buf)*65536 + 32768 + (rel ^ (((rel>>9)&1)<<5))); \
  } } while(0)

#define LDA(buf, q) do { \
  _Pragma("unroll") for (int ml = 0; ml < 2; ml++) \
  _Pragma("unroll") for (int kk = 0; kk < 2; kk++) { \
    int rel = (wm*128 + ((q)*2+ml)*16 + lm)*128 + kk*64 + lg*16; \
    aq[ml][kk] = *(const s16x8*)(smem + (buf)*65536 + (rel ^ (((rel>>9)&1)<<5))); \
  } } while(0)

#define MFMAQ(q) do { \
  __builtin_amdgcn_s_setprio(1); \
  _Pragma("unroll") for (int ml = 0; ml < 2; ml++) \
  _Pragma("unroll") for (int nf = 0; nf < 4; nf++) \
  _Pragma("unroll") for (int kk = 0; kk < 2; kk++) \
    acc[(q)*2+ml][nf] = __builtin_amdgcn_mfma_f32_16x16x32_bf16(aq[ml][kk], bq[nf][kk], acc[(q)*2+ml][nf], 0, 0, 0); \
  __builtin_amdgcn_s_setprio(0); \
} while(0)

template<int EPI>
__global__ __launch_bounds__(512, 2)
void k_gemm256(const u16* __restrict__ A, const u16* __restrict__ W,
               const float* __restrict__ bias, u16* __restrict__ C,
               int M, int N, int K) {
  extern __shared__ char smem[];
  const int tid = threadIdx.x;
  const int lane = tid & 63;
  const int wid = tid >> 6;
  const int lm = lane & 15, lg = lane >> 4;
  const int wm = wid >> 2, wn = wid & 3;

  const int NB = N >> 8;
  const int nwg = gridDim.x;
  const int bid = blockIdx.x;
  const int cpx = nwg >> 3;                 // all our grids are %8==0
  const int swzb = (bid & 7) * cpx + (bid >> 3);
  const int m0 = (swzb / NB) << 8;
  const int n0 = (swzb % NB) << 8;

  // pre-swizzled per-lane global stage pointers
  const u16* pA[2][2];
  const u16* pB[2][2];
#pragma unroll
  for (int h = 0; h < 2; h++)
#pragma unroll
    for (int l = 0; l < 2; l++) {
      int rel = h * 16384 + l * 8192 + tid * 16;
      int sb = rel ^ (((rel >> 9) & 1) << 5);
      int grow = sb >> 7;
      int gcol = (sb & 127) >> 1;
      pA[h][l] = A + (size_t)(m0 + grow) * K + gcol;
      pB[h][l] = W + (size_t)(n0 + grow) * K + gcol;
    }

  f32x4 acc[8][4];
#pragma unroll
  for (int i = 0; i < 8; i++)
#pragma unroll
    for (int j = 0; j < 4; j++) acc[i][j] = (f32x4){0.f, 0.f, 0.f, 0.f};

  s16x8 bq[4][2];
  s16x8 aq[2][2];

  const int NT = K >> 6;   // K-tiles (16 or 64, always even)

  // prologue: tile0 {B,A} -> buf0 ; tile1 {B} -> buf1 ; leaves tile1.B in flight
  STG(pB,1,0,0,0,0); STG(pB,1,0,1,0,0); STG(pB,1,1,0,0,0); STG(pB,1,1,1,0,0);
  STG(pA,0,0,0,0,0); STG(pA,0,0,1,0,0); STG(pA,0,1,0,0,0); STG(pA,0,1,1,0,0);
  STG(pB,1,0,0,1,64); STG(pB,1,0,1,1,64); STG(pB,1,1,0,1,64); STG(pB,1,1,1,1,64);
  VMW4;
  GBAR;

  for (int i = 0; i < (NT >> 1); i++) {
    const int t1k = (2*i + 1) * 64;
    int t2 = 2*i + 2; if (t2 >= NT) t2 -= NT;   // wrapped: keeps vmcnt counts exact
    int t3 = 2*i + 3; if (t3 >= NT) t3 -= NT;
    const int t2k = t2 * 64, t3k = t3 * 64;

    // ph0: read buf0 {B all, A q0}; stage (t1).Ah0 -> buf1.A
    LDB(0); LDA(0,0);
    STG(pA,0,0,0,1,t1k); STG(pA,0,0,1,1,t1k);
    GBAR; MFMAQ(0); GBAR;
    // ph1: A q1; stage (t1).Ah1 -> buf1.A ; (t2).Bh0 -> buf0.B
    LDA(0,1);
    STG(pA,0,1,0,1,t1k); STG(pA,0,1,1,1,t1k);
    STG(pB,1,0,0,0,t2k); STG(pB,1,0,1,0,t2k);
    GBAR; MFMAQ(1); GBAR;
    // ph2: A q2; stage (t2).Bh1 -> buf0.B
    LDA(0,2);
    STG(pB,1,1,0,0,t2k); STG(pB,1,1,1,0,t2k);
    GBAR; MFMAQ(2); GBAR;
    // ph3: A q3; counted drain (t1) complete, (t2).B stays in flight
    LDA(0,3);
    GBAR; MFMAQ(3); VMW4; GBAR;
    // ph4: read buf1 {B all, A q0}; stage (t2).Ah0 -> buf0.A
    LDB(1); LDA(1,0);
    STG(pA,0,0,0,0,t2k); STG(pA,0,0,1,0,t2k);
    GBAR; MFMAQ(0); GBAR;
    // ph5: A q1; stage (t2).Ah1 -> buf0.A
    LDA(1,1);
    STG(pA,0,1,0,0,t2k); STG(pA,0,1,1,0,t2k);
    GBAR; MFMAQ(1); GBAR;
    // ph6: A q2; stage (t3).Bh0 -> buf1.B
    LDA(1,2);
    STG(pB,1,0,0,1,t3k); STG(pB,1,0,1,1,t3k);
    GBAR; MFMAQ(2); GBAR;
    // ph7: A q3; stage (t3).Bh1 -> buf1.B ; counted drain (t2) complete
    LDA(1,3);
    STG(pB,1,1,0,1,t3k); STG(pB,1,1,1,1,t3k);
    GBAR; MFMAQ(3); VMW4; GBAR;
  }

  // epilogue
  float bn[4];
#pragma unroll
  for (int nf = 0; nf < 4; nf++) bn[nf] = bias[n0 + wn*64 + nf*16 + lm];
#pragma unroll
  for (int mf = 0; mf < 8; mf++)
#pragma unroll
    for (int nf = 0; nf < 4; nf++) {
      int col = n0 + wn*64 + nf*16 + lm;
#pragma unroll
      for (int r = 0; r < 4; r++) {
        int row = m0 + wm*128 + mf*16 + lg*4 + r;
        float v = acc[mf][nf][r] + bn[nf];
        if (EPI == 1) v = fmaxf(v, 0.f);
        C[(size_t)row * N + col] = f2bf(v);
      }
    }
}

// ---------------- fused causal attention ----------------
__global__ __launch_bounds__(256)
void k_attn(const u16* __restrict__ qkv, u16* __restrict__ o) {
  const int qb = blockIdx.x;    // 0..3
  const int h  = blockIdx.y;    // 0..15
  const int b  = blockIdx.z;    // 0..63
  const int lane = threadIdx.x & 63;
  const int wave = threadIdx.x >> 6;
  const int lm = lane & 15, lg = lane >> 4;

  __shared__ u16 Ks[64 * 64];      // [k_local][dh]
  __shared__ u16 Vt[64 * 64];      // [dh][k_local]
  __shared__ u16 Ps[4][16 * 64];   // per-wave P [qr][k_local]

  const int q0 = qb * 64 + wave * 16;
  const size_t tokbase = (size_t)b * SS;

  s16x8 aq2[2];
  {
    const u16* qrow = qkv + (tokbase + q0 + lm) * 3072 + h * 64;
    aq2[0] = *(const s16x8*)(qrow + lg * 8);
    aq2[1] = *(const s16x8*)(qrow + 32 + lg * 8);
  }

  f32x4 zero = {0.f, 0.f, 0.f, 0.f};
  f32x4 oacc[4];
#pragma unroll
  for (int j = 0; j < 4; j++) oacc[j] = zero;
  float m_run[4], l_run[4];
#pragma unroll
  for (int r = 0; r < 4; r++) { m_run[r] = -3e38f; l_run[r] = 0.f; }

  const int nkb = qb + 1;
  for (int kb = 0; kb < nkb; ++kb) {
    __syncthreads();
    {
      int krow = threadIdx.x >> 2;
      int seg  = (threadIdx.x & 3) * 16;
      const u16* ksrc = qkv + (tokbase + kb * 64 + krow) * 3072 + 1024 + h * 64 + seg;
      s16x8 v0 = *(const s16x8*)(ksrc);
      s16x8 v1 = *(const s16x8*)(ksrc + 8);
      *(s16x8*)&Ks[krow * 64 + seg] = v0;
      *(s16x8*)&Ks[krow * 64 + seg + 8] = v1;
      const u16* vsrc = qkv + (tokbase + kb * 64 + krow) * 3072 + 2048 + h * 64 + seg;
      s16x8 w0 = *(const s16x8*)(vsrc);
      s16x8 w1 = *(const s16x8*)(vsrc + 8);
#pragma unroll
      for (int e = 0; e < 8; e++) {
        Vt[(seg + e) * 64 + krow]     = (u16)w0[e];
        Vt[(seg + 8 + e) * 64 + krow] = (u16)w1[e];
      }
    }
    __syncthreads();

    f32x4 sfr[4];
#pragma unroll
    for (int j = 0; j < 4; j++) {
      f32x4 acc = zero;
#pragma unroll
      for (int kk = 0; kk < 2; kk++) {
        s16x8 bk = *(const s16x8*)&Ks[(j * 16 + lm) * 64 + kk * 32 + lg * 8];
        acc = __builtin_amdgcn_mfma_f32_16x16x32_bf16(aq2[kk], bk, acc, 0, 0, 0);
      }
      sfr[j] = acc;
    }
    const int colbase = kb * 64;
#pragma unroll
    for (int j = 0; j < 4; j++) {
      int col = colbase + j * 16 + lm;
#pragma unroll
      for (int r = 0; r < 4; r++) {
        int row = q0 + lg * 4 + r;
        float v = sfr[j][r] * 0.125f;
        sfr[j][r] = (col <= row) ? v : -1e30f;
      }
    }
    float mb[4];
#pragma unroll
    for (int r = 0; r < 4; r++) {
      float m = fmaxf(fmaxf(sfr[0][r], sfr[1][r]), fmaxf(sfr[2][r], sfr[3][r]));
#pragma unroll
      for (int off = 1; off < 16; off <<= 1) m = fmaxf(m, __shfl_xor(m, off));
      mb[r] = m;
    }
    float fo[4];
#pragma unroll
    for (int r = 0; r < 4; r++) {
      float mnew = fmaxf(m_run[r], mb[r]);
      fo[r] = __expf(m_run[r] - mnew);
      m_run[r] = mnew;
    }
    float ps[4] = {0.f, 0.f, 0.f, 0.f};
#pragma unroll
    for (int j = 0; j < 4; j++)
#pragma unroll
      for (int r = 0; r < 4; r++) {
        float p = __expf(sfr[j][r] - m_run[r]);
        sfr[j][r] = p;
        ps[r] += p;
      }
#pragma unroll
    for (int r = 0; r < 4; r++) {
#pragma unroll
      for (int off = 1; off < 16; off <<= 1) ps[r] += __shfl_xor(ps[r], off);
      l_run[r] = l_run[r] * fo[r] + ps[r];
    }
#pragma unroll
    for (int j = 0; j < 4; j++)
#pragma unroll
      for (int r = 0; r < 4; r++) oacc[j][r] *= fo[r];
#pragma unroll
    for (int j = 0; j < 4; j++)
#pragma unroll
      for (int r = 0; r < 4; r++)
        Ps[wave][(lg * 4 + r) * 64 + j * 16 + lm] = f2bf(sfr[j][r]);
    asm volatile("" ::: "memory");
#pragma unroll
    for (int kk = 0; kk < 2; kk++) {
      s16x8 pa = *(const s16x8*)&Ps[wave][lm * 64 + kk * 32 + lg * 8];
#pragma unroll
      for (int j2 = 0; j2 < 4; j2++) {
        s16x8 bv = *(const s16x8*)&Vt[(j2 * 16 + lm) * 64 + kk * 32 + lg * 8];
        oacc[j2] = __builtin_amdgcn_mfma_f32_16x16x32_bf16(pa, bv, oacc[j2], 0, 0, 0);
      }
    }
  }
#pragma unroll
  for (int j2 = 0; j2 < 4; j2++)
#pragma unroll
    for (int r = 0; r < 4; r++) {
      int row = q0 + lg * 4 + r;
      float val = oacc[j2][r] / l_run[r];
      o[(tokbase + row) * 1024 + h * 64 + j2 * 16 + lm] = f2bf(val);
    }
}

// ---------------- residual + LayerNorm (tmp is bf16) ----------------
__global__ __launch_bounds__(256)
void k_ln(const float* __restrict__ xin, const u16* __restrict__ tmp,
          const float* __restrict__ gam, const float* __restrict__ bet,
          float* __restrict__ xout, u16* __restrict__ xb) {
  int t = blockIdx.x;
  int tid = threadIdx.x;
  f32x4 v = *(const f32x4*)(xin + (size_t)t * DD + tid * 4);
  u16x4 u4 = *(const u16x4*)(tmp + (size_t)t * DD + tid * 4);
  v[0] += bf2f(u4[0]); v[1] += bf2f(u4[1]); v[2] += bf2f(u4[2]); v[3] += bf2f(u4[3]);
  float s = v[0] + v[1] + v[2] + v[3];
  float s2 = v[0]*v[0] + v[1]*v[1] + v[2]*v[2] + v[3]*v[3];
#pragma unroll
  for (int off = 32; off >= 1; off >>= 1) {
    s  += __shfl_xor(s, off);
    s2 += __shfl_xor(s2, off);
  }
  __shared__ float red[8];
  int w = tid >> 6;
  if ((tid & 63) == 0) { red[w] = s; red[4 + w] = s2; }
  __syncthreads();
  s  = red[0] + red[1] + red[2] + red[3];
  s2 = red[4] + red[5] + red[6] + red[7];
  float mean = s * (1.f / 1024.f);
  float var = s2 * (1.f / 1024.f) - mean * mean;
  float rstd = rsqrtf(var + 1e-5f);
  f32x4 g4 = *(const f32x4*)(gam + tid * 4);
  f32x4 b4 = *(const f32x4*)(bet + tid * 4);
  f32x4 y;
  u16x4 yo;
#pragma unroll
  for (int e = 0; e < 4; e++) {
    y[e] = (v[e] - mean) * rstd * g4[e] + b4[e];
    yo[e] = f2bf(y[e]);
  }
  *(f32x4*)(xout + (size_t)t * DD + tid * 4) = y;
  *(u16x4*)(xb + (size_t)t * DD + tid * 4) = yo;
}

// ---------------- GRU input projection: xp[s][b][g] ----------------
__global__ void k_gruxp(const float* __restrict__ em, const float* __restrict__ Wih,
                        const float* __restrict__ bih, float* __restrict__ xp) {
  int i = blockIdx.x * blockDim.x + threadIdx.x;   // over S*B*300
  if (i >= SS * BB * 300) return;
  int g = i % 300;
  int sb = i / 300;
  int b = sb % BB;
  int s = sb / BB;
  const float* e = em + ((size_t)b * SS + s) * 7;
  const float* w = Wih + (size_t)g * 7;
  float acc = bih[g];
#pragma unroll
  for (int f = 0; f < 7; f++) acc += e[f] * w[f];
  xp[i] = acc;
}

// ---------------- GRU sequential scan: 2 lanes per output, no spill ----------
__global__ __launch_bounds__(640)
void k_gru(const float* __restrict__ xp, const float* __restrict__ Whh,
           const float* __restrict__ bhh, float* __restrict__ emo) {
  const int b = blockIdx.x;
  const int tid = threadIdx.x;
  const int j = tid >> 1;          // 0..319 (j<300 active)
  const int half = tid & 1;
  __shared__ float h[100];
  __shared__ float hp[300];
  float w[50];
  const bool activeJ = (j < 300);
  if (activeJ) {
#pragma unroll
    for (int k = 0; k < 50; k++) w[k] = Whh[(size_t)j * 100 + half * 50 + k];
  }
  float bj = activeJ ? bhh[j] : 0.f;
  if (tid < 100) h[tid] = 0.f;
  __syncthreads();
  for (int s = 0; s < SS; ++s) {
    const float* xr = xp + ((size_t)s * BB + b) * 300;
    float acc0 = 0.f, acc1 = 0.f;
    if (activeJ) {
#pragma unroll
      for (int k = 0; k < 50; k += 2) {
        acc0 += w[k]     * h[half * 50 + k];
        acc1 += w[k + 1] * h[half * 50 + k + 1];
      }
    }
    float acc = acc0 + acc1;
    acc += __shfl_xor(acc, 1);
    if (activeJ && half == 0) hp[j] = acc + bj;
    __syncthreads();
    if (tid < 100) {
      float x0 = xr[tid], x1 = xr[100 + tid], x2 = xr[200 + tid];
      float rr = 1.f / (1.f + __expf(-(x0 + hp[tid])));
      float zz = 1.f / (1.f + __expf(-(x1 + hp[100 + tid])));
      float nx = x2 + rr * hp[200 + tid];
      float e2 = __expf(-2.f * fabsf(nx));
      float th = (1.f - e2) / (1.f + e2);
      float nn = copysignf(th, nx);
      float hn = (1.f - zz) * nn + zz * h[tid];
      h[tid] = hn;
      emo[((size_t)b * SS + s) * 100 + tid] = hn;
    }
    __syncthreads();
  }
}

// ---------------- main-token dot precompute ----------------
__global__ void k_main(const int* __restrict__ d_ids, const int* __restrict__ ut_len,
                       const float* __restrict__ x32, const float* __restrict__ decW,
                       float* __restrict__ md) {
  int b = blockIdx.x;
  int lane = threadIdx.x;   // 64
  int len = ut_len[d_ids[b]];
  const float* xr = x32 + ((size_t)b * SS + (len - 1)) * DD;
  float acc[NCC];
#pragma unroll
  for (int c = 0; c < NCC; c++) acc[c] = 0.f;
  for (int d = lane; d < DD; d += 64) {
    float xv = xr[d];
#pragma unroll
    for (int c = 0; c < NCC; c++) acc[c] += xv * decW[(size_t)c * 2148 + 1024 + d];
  }
#pragma unroll
  for (int c = 0; c < NCC; c++) {
#pragma unroll
    for (int off = 32; off >= 1; off >>= 1) acc[c] += __shfl_xor(acc[c], off);
  }
  if (lane == 0) {
#pragma unroll
    for (int c = 0; c < NCC; c++) md[b * NCC + c] = acc[c];
  }
}

// ---------------- decoder ----------------
__global__ __launch_bounds__(256)
void k_dec(const float* __restrict__ x32, const float* __restrict__ emo,
           const float* __restrict__ md, const float* __restrict__ decW,
           const float* __restrict__ decb, const int* __restrict__ d_ids,
           const int* __restrict__ ut_len, float* __restrict__ out) {
  int grp = threadIdx.x >> 6, lane = threadIdx.x & 63;
  int t = blockIdx.x * 4 + grp;
  int b = t / SS, s = t % SS;
  int len = ut_len[d_ids[b]];
  bool valid = s < len;
  float acc[NCC];
#pragma unroll
  for (int c = 0; c < NCC; c++) acc[c] = 0.f;
  if (valid) {
    const float* xr = x32 + (size_t)t * DD;
    for (int d = lane; d < DD; d += 64) {
      float xv = xr[d];
#pragma unroll
      for (int c = 0; c < NCC; c++) acc[c] += xv * decW[(size_t)c * 2148 + d];
    }
  }
  {
    const float* er = emo + (size_t)t * GHH;
    for (int d = lane; d < GHH; d += 64) {
      float ev = er[d];
#pragma unroll
      for (int c = 0; c < NCC; c++) acc[c] += ev * decW[(size_t)c * 2148 + 2048 + d];
    }
  }
#pragma unroll
  for (int c = 0; c < NCC; c++) {
#pragma unroll
    for (int off = 32; off >= 1; off >>= 1) acc[c] += __shfl_xor(acc[c], off);
  }
  if (lane == 0) {
#pragma unroll
    for (int c = 0; c < NCC; c++) {
      float v = acc[c] + (valid ? md[b * NCC + c] : 0.f) + decb[c];
      out[(size_t)t * NCC + c] = v;
    }
  }
}

// ---------------- launch ----------------
extern "C" void kernel_launch(void* const* d_in, const int* in_sizes, int n_in,
                              void* d_out, int out_size, void* d_ws, size_t ws_size,
                              hipStream_t stream) {
  const int*   src    = (const int*)d_in[0];
  const float* em_seq = (const float*)d_in[1];
  const int*   d_ids  = (const int*)d_in[2];
  const int*   ut_len = (const int*)d_in[3];
  const float* emb    = (const float*)d_in[4];
  const float* Wqkv   = (const float*)d_in[5];
  const float* bqkv   = (const float*)d_in[6];
  const float* Wo     = (const float*)d_in[7];
  const float* bo     = (const float*)d_in[8];
  const float* W1     = (const float*)d_in[9];
  const float* b1     = (const float*)d_in[10];
  const float* W2     = (const float*)d_in[11];
  const float* b2     = (const float*)d_in[12];
  const float* ln1g   = (const float*)d_in[13];
  const float* ln1b   = (const float*)d_in[14];
  const float* ln2g   = (const float*)d_in[15];
  const float* ln2b   = (const float*)d_in[16];
  const float* gWih   = (const float*)d_in[17];
  const float* gWhh   = (const float*)d_in[18];
  const float* gbih   = (const float*)d_in[19];
  const float* gbhh   = (const float*)d_in[20];
  const float* decW   = (const float*)d_in[21];
  const float* decb   = (const float*)d_in[22];
  float* out = (float*)d_out;

  char* wsp = (char*)d_ws;
  auto take = [&](size_t n) { char* p = wsp; wsp += (n + 255) & ~(size_t)255; return p; };

  u16*   wqkvb = (u16*)take((size_t)3072 * 1024 * 2);
  u16*   wob   = (u16*)take((size_t)1024 * 1024 * 2);
  u16*   w1b   = (u16*)take((size_t)4096 * 1024 * 2);
  u16*   w2b   = (u16*)take((size_t)1024 * 4096 * 2);
  float* pe    = (float*)take((size_t)SS * DD * 4);
  float* x32   = (float*)take((size_t)TT * DD * 4);
  u16*   xb    = (u16*)take((size_t)TT * DD * 2);
  u16*   big   = (u16*)take((size_t)TT * FFN * 2);   // qkv (T x 3072) or ff1 (T x 4096)
  u16*   ob    = (u16*)take((size_t)TT * DD * 2);
  u16*   tmp16 = (u16*)take((size_t)TT * DD * 2);
  float* xp    = (float*)take((size_t)SS * BB * 300 * 4);
  float* emo   = (float*)take((size_t)BB * SS * GHH * 4);
  float* md    = (float*)take((size_t)BB * NCC * 4);

  // allow 128 KiB dynamic LDS (no-op if already permitted)
  (void)hipFuncSetAttribute((const void*)&k_gemm256<0>,
      hipFuncAttributeMaxDynamicSharedMemorySize, 131072);
  (void)hipFuncSetAttribute((const void*)&k_gemm256<1>,
      hipFuncAttributeMaxDynamicSharedMemorySize, 131072);

  // GRU path (independent of transformer)
  k_gruxp<<<(SS * BB * 300 + 255) / 256, 256, 0, stream>>>(em_seq, gWih, gbih, xp);
  k_gru<<<BB, 640, 0, stream>>>(xp, gWhh, gbhh, emo);

  // embedding + positional encoding
  k_pe<<<(SS * DD / 2 + 255) / 256, 256, 0, stream>>>(pe);
  k_embed<<<TT * DD / 4 / 256, 256, 0, stream>>>(src, emb, pe, x32, xb);

  for (int l = 0; l < LL; ++l) {
    k_f2bf<<<2048, 256, 0, stream>>>(Wqkv + (size_t)l * 3072 * 1024, wqkvb, 3072 * 1024 / 4);
    k_f2bf<<<2048, 256, 0, stream>>>(Wo   + (size_t)l * 1024 * 1024, wob,   1024 * 1024 / 4);
    k_f2bf<<<2048, 256, 0, stream>>>(W1   + (size_t)l * 4096 * 1024, w1b,   4096 * 1024 / 4);
    k_f2bf<<<2048, 256, 0, stream>>>(W2   + (size_t)l * 1024 * 4096, w2b,   1024 * 4096 / 4);

    // QKV projection: [16384,3072] = xb @ Wqkv^T
    k_gemm256<0><<<(TT/256) * (3072/256), 512, 131072, stream>>>(
        xb, wqkvb, bqkv + (size_t)l * 3072, big, TT, 3072, 1024);
    // attention
    k_attn<<<dim3(4, HH, BB), 256, 0, stream>>>(big, ob);
    // output projection (bf16 out to tmp16)
    k_gemm256<0><<<(TT/256) * (1024/256), 512, 131072, stream>>>(
        ob, wob, bo + (size_t)l * 1024, tmp16, TT, 1024, 1024);
    // residual + LN1
    k_ln<<<TT, 256, 0, stream>>>(x32, tmp16, ln1g + (size_t)l * DD, ln1b + (size_t)l * DD, x32, xb);
    // FFN1 (relu)
    k_gemm256<1><<<(TT/256) * (4096/256), 512, 131072, stream>>>(
        xb, w1b, b1 + (size_t)l * 4096, big, TT, 4096, 1024);
    // FFN2
    k_gemm256<0><<<(TT/256) * (1024/256), 512, 131072, stream>>>(
        big, w2b, b2 + (size_t)l * 1024, tmp16, TT, 1024, 4096);
    // residual + LN2
    k_ln<<<TT, 256, 0, stream>>>(x32, tmp16, ln2g + (size_t)l * DD, ln2b + (size_t)l * DD, x32, xb);
  }

  // decoder
  k_main<<<BB, 64, 0, stream>>>(d_ids, ut_len, x32, decW, md);
  k_dec<<<TT / 4, 256, 0, stream>>>(x32, emo, md, decW, decb, d_ids, ut_len, out);
}

// Round 3
// 2532.684 us; speedup vs baseline: 1.4333x; 1.0491x over previous
//
#include <hip/hip_runtime.h>
#include <hip/hip_bf16.h>
#include <math.h>

// Problem constants
#define BB 64
#define SS 256
#define DD 1024
#define HH 16
#define FFN 4096
#define GHH 100
#define NCC 7
#define LL 4
#define TT (BB*SS)          // 16384 tokens
#define DHH 64

typedef unsigned short u16;
typedef unsigned int u32;
typedef __attribute__((ext_vector_type(4))) float f32x4;
typedef __attribute__((ext_vector_type(8))) short s16x8;
typedef __attribute__((ext_vector_type(4))) unsigned short u16x4;

__device__ __forceinline__ u16 f2bf(float f) {
  union { float f; u32 u; } x; x.f = f;
  u32 r = x.u + 0x7FFFu + ((x.u >> 16) & 1u);
  return (u16)(r >> 16);
}
__device__ __forceinline__ float bf2f(u16 b) {
  union { u32 u; float f; } x; x.u = ((u32)b) << 16;
  return x.f;
}

// ---------------- fused fp32 -> bf16 convert (4 tensors) ----------------
__global__ void k_f2bf4(const float* __restrict__ s0, u16* __restrict__ d0, int n0,
                        const float* __restrict__ s1, u16* __restrict__ d1, int n1,
                        const float* __restrict__ s2, u16* __restrict__ d2, int n2,
                        const float* __restrict__ s3, u16* __restrict__ d3, int n3) {
  int stride = gridDim.x * blockDim.x;
  int total = n0 + n1 + n2 + n3;
  for (int i = blockIdx.x * blockDim.x + threadIdx.x; i < total; i += stride) {
    const float* s; u16* d; int j = i;
    if (j < n0) { s = s0; d = d0; }
    else {
      j -= n0;
      if (j < n1) { s = s1; d = d1; }
      else {
        j -= n1;
        if (j < n2) { s = s2; d = d2; }
        else { j -= n2; s = s3; d = d3; }
      }
    }
    f32x4 v = *(const f32x4*)(s + (size_t)j * 4);
    u16x4 o;
    o[0] = f2bf(v[0]); o[1] = f2bf(v[1]); o[2] = f2bf(v[2]); o[3] = f2bf(v[3]);
    *(u16x4*)(d + (size_t)j * 4) = o;
  }
}

// ---------------- positional encoding ----------------
__global__ void k_pe(float* __restrict__ pe) {
  int i = blockIdx.x * blockDim.x + threadIdx.x;     // over S*D/2
  if (i >= SS * DD / 2) return;
  int s = i / (DD / 2), j = i % (DD / 2);
  float div = __expf((float)(2 * j) * (-9.210340371976184f / (float)DD));
  float a = (float)s * div;
  pe[s * DD + 2 * j]     = sinf(a);
  pe[s * DD + 2 * j + 1] = cosf(a);
}

// ---------------- embedding + PE ----------------
__global__ void k_embed(const int* __restrict__ src, const float* __restrict__ emb,
                        const float* __restrict__ pe, float* __restrict__ x32,
                        u16* __restrict__ xb) {
  int i = blockIdx.x * blockDim.x + threadIdx.x;     // over T*D/4
  if (i >= TT * DD / 4) return;
  int t = i / (DD / 4);
  int d4 = (i % (DD / 4)) * 4;
  int s = t % SS;
  int tok = src[t];
  f32x4 e = *(const f32x4*)(emb + (size_t)tok * DD + d4);
  f32x4 p = *(const f32x4*)(pe + (size_t)s * DD + d4);
  f32x4 r;
  r[0] = e[0] * 32.0f + p[0]; r[1] = e[1] * 32.0f + p[1];
  r[2] = e[2] * 32.0f + p[2]; r[3] = e[3] * 32.0f + p[3];
  *(f32x4*)(x32 + (size_t)t * DD + d4) = r;
  u16x4 o;
  o[0] = f2bf(r[0]); o[1] = f2bf(r[1]); o[2] = f2bf(r[2]); o[3] = f2bf(r[3]);
  *(u16x4*)(xb + (size_t)t * DD + d4) = o;
}

// ---------------- 256x256 8-phase GEMM (T1+T2+T3+T4+T5) ----------------
#define MEMF asm volatile("" ::: "memory")
#define GBAR do { MEMF; __builtin_amdgcn_sched_barrier(0); __builtin_amdgcn_s_barrier(); __builtin_amdgcn_sched_barrier(0); MEMF; } while(0)
#define VMW4 asm volatile("s_waitcnt vmcnt(4)" ::: "memory")

#define STG(P, isB, h, l, buf, kt) \
  __builtin_amdgcn_global_load_lds( \
    (const __attribute__((address_space(1))) u32*)(P[h][l] + (kt)), \
    (__attribute__((address_space(3))) u32*)(smem + (buf)*65536 + (isB)*32768 + (h)*16384 + (l)*8192 + wid*1024), \
    16, 0, 0)

#define LDB(buf) do { \
  _Pragma("unroll") for (int nf = 0; nf < 4; nf++) \
  _Pragma("unroll") for (int kk = 0; kk < 2; kk++) { \
    int rel = (wn*64 + nf*16 + lm)*128 + kk*64 + lg*16; \
    bq[nf][kk] = *(const s16x8*)(smem + (buf)*65536 + 32768 + (rel ^ (((rel>>9)&1)<<5))); \
  } } while(0)

#define LDA(buf, q) do { \
  _Pragma("unroll") for (int ml = 0; ml < 2; ml++) \
  _Pragma("unroll") for (int kk = 0; kk < 2; kk++) { \
    int rel = (wm*128 + ((q)*2+ml)*16 + lm)*128 + kk*64 + lg*16; \
    aq[ml][kk] = *(const s16x8*)(smem + (buf)*65536 + (rel ^ (((rel>>9)&1)<<5))); \
  } } while(0)

#define MFMAQ(q) do { \
  __builtin_amdgcn_s_setprio(1); \
  _Pragma("unroll") for (int ml = 0; ml < 2; ml++) \
  _Pragma("unroll") for (int nf = 0; nf < 4; nf++) \
  _Pragma("unroll") for (int kk = 0; kk < 2; kk++) \
    acc[(q)*2+ml][nf] = __builtin_amdgcn_mfma_f32_16x16x32_bf16(aq[ml][kk], bq[nf][kk], acc[(q)*2+ml][nf], 0, 0, 0); \
  __builtin_amdgcn_s_setprio(0); \
} while(0)

template<int EPI>
__global__ __launch_bounds__(512, 2)
void k_gemm256(const u16* __restrict__ A, const u16* __restrict__ W,
               const float* __restrict__ bias, u16* __restrict__ C,
               int M, int N, int K) {
  extern __shared__ char smem[];
  const int tid = threadIdx.x;
  const int lane = tid & 63;
  const int wid = tid >> 6;
  const int lm = lane & 15, lg = lane >> 4;
  const int wm = wid >> 2, wn = wid & 3;

  const int NB = N >> 8;
  const int nwg = gridDim.x;
  const int bid = blockIdx.x;
  const int cpx = nwg >> 3;
  const int swzb = (bid & 7) * cpx + (bid >> 3);
  const int m0 = (swzb / NB) << 8;
  const int n0 = (swzb % NB) << 8;

  const u16* pA[2][2];
  const u16* pB[2][2];
#pragma unroll
  for (int h = 0; h < 2; h++)
#pragma unroll
    for (int l = 0; l < 2; l++) {
      int rel = h * 16384 + l * 8192 + tid * 16;
      int sb = rel ^ (((rel >> 9) & 1) << 5);
      int grow = sb >> 7;
      int gcol = (sb & 127) >> 1;
      pA[h][l] = A + (size_t)(m0 + grow) * K + gcol;
      pB[h][l] = W + (size_t)(n0 + grow) * K + gcol;
    }

  f32x4 acc[8][4];
#pragma unroll
  for (int i = 0; i < 8; i++)
#pragma unroll
    for (int j = 0; j < 4; j++) acc[i][j] = (f32x4){0.f, 0.f, 0.f, 0.f};

  s16x8 bq[4][2];
  s16x8 aq[2][2];

  const int NT = K >> 6;

  STG(pB,1,0,0,0,0); STG(pB,1,0,1,0,0); STG(pB,1,1,0,0,0); STG(pB,1,1,1,0,0);
  STG(pA,0,0,0,0,0); STG(pA,0,0,1,0,0); STG(pA,0,1,0,0,0); STG(pA,0,1,1,0,0);
  STG(pB,1,0,0,1,64); STG(pB,1,0,1,1,64); STG(pB,1,1,0,1,64); STG(pB,1,1,1,1,64);
  VMW4;
  GBAR;

  for (int i = 0; i < (NT >> 1); i++) {
    const int t1k = (2*i + 1) * 64;
    int t2 = 2*i + 2; if (t2 >= NT) t2 -= NT;
    int t3 = 2*i + 3; if (t3 >= NT) t3 -= NT;
    const int t2k = t2 * 64, t3k = t3 * 64;

    LDB(0); LDA(0,0);
    STG(pA,0,0,0,1,t1k); STG(pA,0,0,1,1,t1k);
    GBAR; MFMAQ(0); GBAR;
    LDA(0,1);
    STG(pA,0,1,0,1,t1k); STG(pA,0,1,1,1,t1k);
    STG(pB,1,0,0,0,t2k); STG(pB,1,0,1,0,t2k);
    GBAR; MFMAQ(1); GBAR;
    LDA(0,2);
    STG(pB,1,1,0,0,t2k); STG(pB,1,1,1,0,t2k);
    GBAR; MFMAQ(2); GBAR;
    LDA(0,3);
    GBAR; MFMAQ(3); VMW4; GBAR;
    LDB(1); LDA(1,0);
    STG(pA,0,0,0,0,t2k); STG(pA,0,0,1,0,t2k);
    GBAR; MFMAQ(0); GBAR;
    LDA(1,1);
    STG(pA,0,1,0,0,t2k); STG(pA,0,1,1,0,t2k);
    GBAR; MFMAQ(1); GBAR;
    LDA(1,2);
    STG(pB,1,0,0,1,t3k); STG(pB,1,0,1,1,t3k);
    GBAR; MFMAQ(2); GBAR;
    LDA(1,3);
    STG(pB,1,1,0,1,t3k); STG(pB,1,1,1,1,t3k);
    GBAR; MFMAQ(3); VMW4; GBAR;
  }

  float bn[4];
#pragma unroll
  for (int nf = 0; nf < 4; nf++) bn[nf] = bias[n0 + wn*64 + nf*16 + lm];
#pragma unroll
  for (int mf = 0; mf < 8; mf++)
#pragma unroll
    for (int nf = 0; nf < 4; nf++) {
      int col = n0 + wn*64 + nf*16 + lm;
#pragma unroll
      for (int r = 0; r < 4; r++) {
        int row = m0 + wm*128 + mf*16 + lg*4 + r;
        float v = acc[mf][nf][r] + bn[nf];
        if (EPI == 1) v = fmaxf(v, 0.f);
        C[(size_t)row * N + col] = f2bf(v);
      }
    }
}

// ---------------- fused causal attention: block=(h,b), wave=q-block ----------
__global__ __launch_bounds__(256, 2)
void k_attn(const u16* __restrict__ qkv, u16* __restrict__ o) {
  const int h = blockIdx.x;     // 0..15
  const int b = blockIdx.y;     // 0..63
  const int lane = threadIdx.x & 63;
  const int w = threadIdx.x >> 6;    // q-block 0..3 (64 rows each)
  const int lm = lane & 15, lg = lane >> 4;

  __shared__ u16 Ks[64 * 64];       // [k_local][dh]
  __shared__ u16 Vt[64 * 64];       // [dh][k_local]
  __shared__ u16 Ps[4][64 * 64];    // per-wave P [q_local][k_local]

  const size_t tokbase = (size_t)b * SS;

  // Q fragments persistent: rows w*64 + mf*16 + lm, dh = kk*32 + lg*8
  s16x8 aq[4][2];
#pragma unroll
  for (int mf = 0; mf < 4; mf++) {
    const u16* qrow = qkv + (tokbase + w * 64 + mf * 16 + lm) * 3072 + h * 64;
#pragma unroll
    for (int kk = 0; kk < 2; kk++)
      aq[mf][kk] = *(const s16x8*)(qrow + kk * 32 + lg * 8);
  }

  f32x4 zero = {0.f, 0.f, 0.f, 0.f};
  f32x4 oacc[4][4];
#pragma unroll
  for (int mf = 0; mf < 4; mf++)
#pragma unroll
    for (int df = 0; df < 4; df++) oacc[mf][df] = zero;
  float m_run[16], l_run[16];
#pragma unroll
  for (int r = 0; r < 16; r++) { m_run[r] = -3e38f; l_run[r] = 0.f; }

  for (int kb = 0; kb < 4; kb++) {
    __syncthreads();
    // stage K block + V^T block (all 256 threads)
    {
      int krow = threadIdx.x >> 2;
      int seg  = (threadIdx.x & 3) * 16;
      const u16* ksrc = qkv + (tokbase + kb * 64 + krow) * 3072 + 1024 + h * 64 + seg;
      s16x8 v0 = *(const s16x8*)(ksrc);
      s16x8 v1 = *(const s16x8*)(ksrc + 8);
      *(s16x8*)&Ks[krow * 64 + seg] = v0;
      *(s16x8*)&Ks[krow * 64 + seg + 8] = v1;
      const u16* vsrc = qkv + (tokbase + kb * 64 + krow) * 3072 + 2048 + h * 64 + seg;
      s16x8 w0 = *(const s16x8*)(vsrc);
      s16x8 w1 = *(const s16x8*)(vsrc + 8);
#pragma unroll
      for (int e = 0; e < 8; e++) {
        Vt[(seg + e) * 64 + krow]     = (u16)w0[e];
        Vt[(seg + 8 + e) * 64 + krow] = (u16)w1[e];
      }
    }
    __syncthreads();
    if (w < kb) continue;   // inactive wave: barriers already matched this iter

    // K fragments shared across mf
    s16x8 bk[4][2];
#pragma unroll
    for (int nf = 0; nf < 4; nf++)
#pragma unroll
      for (int kk = 0; kk < 2; kk++)
        bk[nf][kk] = *(const s16x8*)&Ks[(nf * 16 + lm) * 64 + kk * 32 + lg * 8];

    const int colbase = kb * 64;
#pragma unroll
    for (int mf = 0; mf < 4; mf++) {
      f32x4 sfr[4];
#pragma unroll
      for (int nf = 0; nf < 4; nf++) {
        f32x4 acc = zero;
#pragma unroll
        for (int kk = 0; kk < 2; kk++)
          acc = __builtin_amdgcn_mfma_f32_16x16x32_bf16(aq[mf][kk], bk[nf][kk], acc, 0, 0, 0);
        sfr[nf] = acc;
      }
      // scale + causal mask
      const int rowbase = w * 64 + mf * 16 + lg * 4;
#pragma unroll
      for (int nf = 0; nf < 4; nf++) {
        int col = colbase + nf * 16 + lm;
#pragma unroll
        for (int r = 0; r < 4; r++) {
          float v = sfr[nf][r] * 0.125f;
          sfr[nf][r] = (col <= rowbase + r) ? v : -1e30f;
        }
      }
      // online softmax for this mf's 4 row-stats
#pragma unroll
      for (int r = 0; r < 4; r++) {
        float m = fmaxf(fmaxf(sfr[0][r], sfr[1][r]), fmaxf(sfr[2][r], sfr[3][r]));
#pragma unroll
        for (int off = 1; off < 16; off <<= 1) m = fmaxf(m, __shfl_xor(m, off));
        int idx = mf * 4 + r;
        float mnew = fmaxf(m_run[idx], m);
        float fo = __expf(m_run[idx] - mnew);
        m_run[idx] = mnew;
        float ps = 0.f;
#pragma unroll
        for (int nf = 0; nf < 4; nf++) {
          float p = __expf(sfr[nf][r] - mnew);
          sfr[nf][r] = p;
          ps += p;
        }
#pragma unroll
        for (int off = 1; off < 16; off <<= 1) ps += __shfl_xor(ps, off);
        l_run[idx] = l_run[idx] * fo + ps;
#pragma unroll
        for (int df = 0; df < 4; df++) oacc[mf][df][r] *= fo;
      }
      // P -> LDS (wave-private region)
#pragma unroll
      for (int nf = 0; nf < 4; nf++)
#pragma unroll
        for (int r = 0; r < 4; r++)
          Ps[w][(mf * 16 + lg * 4 + r) * 64 + nf * 16 + lm] = f2bf(sfr[nf][r]);
    }
    asm volatile("" ::: "memory");
    // O += P V : bv shared across mf
    s16x8 bv[4][2];
#pragma unroll
    for (int df = 0; df < 4; df++)
#pragma unroll
      for (int kk = 0; kk < 2; kk++)
        bv[df][kk] = *(const s16x8*)&Vt[(df * 16 + lm) * 64 + kk * 32 + lg * 8];
#pragma unroll
    for (int mf = 0; mf < 4; mf++) {
      s16x8 pa[2];
#pragma unroll
      for (int kk = 0; kk < 2; kk++)
        pa[kk] = *(const s16x8*)&Ps[w][(mf * 16 + lm) * 64 + kk * 32 + lg * 8];
#pragma unroll
      for (int df = 0; df < 4; df++)
#pragma unroll
        for (int kk = 0; kk < 2; kk++)
          oacc[mf][df] = __builtin_amdgcn_mfma_f32_16x16x32_bf16(pa[kk], bv[df][kk], oacc[mf][df], 0, 0, 0);
    }
  }

  // normalize + store
#pragma unroll
  for (int mf = 0; mf < 4; mf++)
#pragma unroll
    for (int df = 0; df < 4; df++)
#pragma unroll
      for (int r = 0; r < 4; r++) {
        int row = w * 64 + mf * 16 + lg * 4 + r;
        float val = oacc[mf][df][r] / l_run[mf * 4 + r];
        o[(tokbase + row) * 1024 + h * 64 + df * 16 + lm] = f2bf(val);
      }
}

// ---------------- residual + LayerNorm (tmp is bf16) ----------------
__global__ __launch_bounds__(256)
void k_ln(const float* __restrict__ xin, const u16* __restrict__ tmp,
          const float* __restrict__ gam, const float* __restrict__ bet,
          float* __restrict__ xout, u16* __restrict__ xb) {
  int t = blockIdx.x;
  int tid = threadIdx.x;
  f32x4 v = *(const f32x4*)(xin + (size_t)t * DD + tid * 4);
  u16x4 u4 = *(const u16x4*)(tmp + (size_t)t * DD + tid * 4);
  v[0] += bf2f(u4[0]); v[1] += bf2f(u4[1]); v[2] += bf2f(u4[2]); v[3] += bf2f(u4[3]);
  float s = v[0] + v[1] + v[2] + v[3];
  float s2 = v[0]*v[0] + v[1]*v[1] + v[2]*v[2] + v[3]*v[3];
#pragma unroll
  for (int off = 32; off >= 1; off >>= 1) {
    s  += __shfl_xor(s, off);
    s2 += __shfl_xor(s2, off);
  }
  __shared__ float red[8];
  int w = tid >> 6;
  if ((tid & 63) == 0) { red[w] = s; red[4 + w] = s2; }
  __syncthreads();
  s  = red[0] + red[1] + red[2] + red[3];
  s2 = red[4] + red[5] + red[6] + red[7];
  float mean = s * (1.f / 1024.f);
  float var = s2 * (1.f / 1024.f) - mean * mean;
  float rstd = rsqrtf(var + 1e-5f);
  f32x4 g4 = *(const f32x4*)(gam + tid * 4);
  f32x4 b4 = *(const f32x4*)(bet + tid * 4);
  f32x4 y;
  u16x4 yo;
#pragma unroll
  for (int e = 0; e < 4; e++) {
    y[e] = (v[e] - mean) * rstd * g4[e] + b4[e];
    yo[e] = f2bf(y[e]);
  }
  *(f32x4*)(xout + (size_t)t * DD + tid * 4) = y;
  *(u16x4*)(xb + (size_t)t * DD + tid * 4) = yo;
}

// ---------------- GRU: fused input proj + 1-barrier scan ----------------
// 200 active threads: pair (i, half) computes half of all 3 gate dots for
// hidden unit i; h double-buffered in LDS (1 barrier/step); uniform f32x4
// broadcast reads of h serve all 3 gates.
__global__ __launch_bounds__(256, 1)
void k_gru(const float* __restrict__ em, const float* __restrict__ Wih,
           const float* __restrict__ bih, const float* __restrict__ Whh,
           const float* __restrict__ bhh, float* __restrict__ emo) {
  const int b = blockIdx.x;
  const int tid = threadIdx.x;
  const int i = tid >> 1;
  const int half = tid & 1;
  const bool act = tid < 200;
  __shared__ float h[2][104];     // unit j at slot j + (j>=50 ? 2 : 0)

  float wr[52], wz[52], wn[52];
  float wir[7], wiz[7], win[7];
  float br = 0.f, bz = 0.f, bn = 0.f, xbr = 0.f, xbz = 0.f, xbn = 0.f;
  if (act) {
#pragma unroll
    for (int k = 0; k < 52; k++) {
      int kk = half * 50 + k;
      bool ok = k < 50;
      wr[k] = ok ? Whh[(size_t)i * 100 + kk]         : 0.f;
      wz[k] = ok ? Whh[(size_t)(100 + i) * 100 + kk] : 0.f;
      wn[k] = ok ? Whh[(size_t)(200 + i) * 100 + kk] : 0.f;
    }
#pragma unroll
    for (int f = 0; f < 7; f++) {
      wir[f] = Wih[i * 7 + f];
      wiz[f] = Wih[(100 + i) * 7 + f];
      win[f] = Wih[(200 + i) * 7 + f];
    }
    br = bhh[i]; bz = bhh[100 + i]; bn = bhh[200 + i];
    xbr = bih[i]; xbz = bih[100 + i]; xbn = bih[200 + i];
  }
  if (tid < 100) h[0][tid + (tid >= 50 ? 2 : 0)] = 0.f;
  if (tid < 2) { h[tid][50] = 0.f; h[tid][51] = 0.f; h[tid][102] = 0.f; h[tid][103] = 0.f; }
  __syncthreads();

  const float* eb = em + (size_t)b * SS * 7;
  float e[7];
#pragma unroll
  for (int f = 0; f < 7; f++) e[f] = eb[f];

  for (int s = 0; s < SS; ++s) {
    const int cur = s & 1, nxt = cur ^ 1;
    // input projection for this step (only half==0's values are used)
    float sr = xbr, sz = xbz, sn = xbn;
#pragma unroll
    for (int f = 0; f < 7; f++) {
      sr += wir[f] * e[f]; sz += wiz[f] * e[f]; sn += win[f] * e[f];
    }
    // prefetch next step's em row (hidden under matvec)
    {
      int sp = (s + 1 < SS) ? s + 1 : s;
#pragma unroll
      for (int f = 0; f < 7; f++) e[f] = eb[sp * 7 + f];
    }
    // matvec: one uniform h read serves all 3 gates
    const float* hb = &h[cur][half * 52];
    float ar = 0.f, az = 0.f, an = 0.f;
#pragma unroll
    for (int k = 0; k < 52; k += 4) {
      f32x4 hv = *(const f32x4*)(hb + k);
      ar += wr[k]*hv[0] + wr[k+1]*hv[1] + wr[k+2]*hv[2] + wr[k+3]*hv[3];
      az += wz[k]*hv[0] + wz[k+1]*hv[1] + wz[k+2]*hv[2] + wz[k+3]*hv[3];
      an += wn[k]*hv[0] + wn[k+1]*hv[1] + wn[k+2]*hv[2] + wn[k+3]*hv[3];
    }
    ar += __shfl_xor(ar, 1);
    az += __shfl_xor(az, 1);
    an += __shfl_xor(an, 1);
    if (act && half == 0) {
      float hold = h[cur][i + (i >= 50 ? 2 : 0)];
      float rr = 1.f / (1.f + __expf(-(sr + ar + br)));
      float zz = 1.f / (1.f + __expf(-(sz + az + bz)));
      float nx = sn + rr * (an + bn);
      float e2 = __expf(-2.f * fabsf(nx));
      float th = (1.f - e2) / (1.f + e2);
      float nn = copysignf(th, nx);
      float hn = (1.f - zz) * nn + zz * hold;
      h[nxt][i + (i >= 50 ? 2 : 0)] = hn;
      emo[((size_t)b * SS + s) * GHH + i] = hn;
    }
    __syncthreads();
  }
}

// ---------------- main-token dot precompute ----------------
__global__ void k_main(const int* __restrict__ d_ids, const int* __restrict__ ut_len,
                       const float* __restrict__ x32, const float* __restrict__ decW,
                       float* __restrict__ md) {
  int b = blockIdx.x;
  int lane = threadIdx.x;   // 64
  int len = ut_len[d_ids[b]];
  const float* xr = x32 + ((size_t)b * SS + (len - 1)) * DD;
  float acc[NCC];
#pragma unroll
  for (int c = 0; c < NCC; c++) acc[c] = 0.f;
  for (int d = lane; d < DD; d += 64) {
    float xv = xr[d];
#pragma unroll
    for (int c = 0; c < NCC; c++) acc[c] += xv * decW[(size_t)c * 2148 + 1024 + d];
  }
#pragma unroll
  for (int c = 0; c < NCC; c++) {
#pragma unroll
    for (int off = 32; off >= 1; off >>= 1) acc[c] += __shfl_xor(acc[c], off);
  }
  if (lane == 0) {
#pragma unroll
    for (int c = 0; c < NCC; c++) md[b * NCC + c] = acc[c];
  }
}

// ---------------- decoder ----------------
__global__ __launch_bounds__(256)
void k_dec(const float* __restrict__ x32, const float* __restrict__ emo,
           const float* __restrict__ md, const float* __restrict__ decW,
           const float* __restrict__ decb, const int* __restrict__ d_ids,
           const int* __restrict__ ut_len, float* __restrict__ out) {
  int grp = threadIdx.x >> 6, lane = threadIdx.x & 63;
  int t = blockIdx.x * 4 + grp;
  int b = t / SS, s = t % SS;
  int len = ut_len[d_ids[b]];
  bool valid = s < len;
  float acc[NCC];
#pragma unroll
  for (int c = 0; c < NCC; c++) acc[c] = 0.f;
  if (valid) {
    const float* xr = x32 + (size_t)t * DD;
    for (int d = lane; d < DD; d += 64) {
      float xv = xr[d];
#pragma unroll
      for (int c = 0; c < NCC; c++) acc[c] += xv * decW[(size_t)c * 2148 + d];
    }
  }
  {
    const float* er = emo + (size_t)t * GHH;
    for (int d = lane; d < GHH; d += 64) {
      float ev = er[d];
#pragma unroll
      for (int c = 0; c < NCC; c++) acc[c] += ev * decW[(size_t)c * 2148 + 2048 + d];
    }
  }
#pragma unroll
  for (int c = 0; c < NCC; c++) {
#pragma unroll
    for (int off = 32; off >= 1; off >>= 1) acc[c] += __shfl_xor(acc[c], off);
  }
  if (lane == 0) {
#pragma unroll
    for (int c = 0; c < NCC; c++) {
      float v = acc[c] + (valid ? md[b * NCC + c] : 0.f) + decb[c];
      out[(size_t)t * NCC + c] = v;
    }
  }
}

// ---------------- launch ----------------
extern "C" void kernel_launch(void* const* d_in, const int* in_sizes, int n_in,
                              void* d_out, int out_size, void* d_ws, size_t ws_size,
                              hipStream_t stream) {
  const int*   src    = (const int*)d_in[0];
  const float* em_seq = (const float*)d_in[1];
  const int*   d_ids  = (const int*)d_in[2];
  const int*   ut_len = (const int*)d_in[3];
  const float* emb    = (const float*)d_in[4];
  const float* Wqkv   = (const float*)d_in[5];
  const float* bqkv   = (const float*)d_in[6];
  const float* Wo     = (const float*)d_in[7];
  const float* bo     = (const float*)d_in[8];
  const float* W1     = (const float*)d_in[9];
  const float* b1     = (const float*)d_in[10];
  const float* W2     = (const float*)d_in[11];
  const float* b2     = (const float*)d_in[12];
  const float* ln1g   = (const float*)d_in[13];
  const float* ln1b   = (const float*)d_in[14];
  const float* ln2g   = (const float*)d_in[15];
  const float* ln2b   = (const float*)d_in[16];
  const float* gWih   = (const float*)d_in[17];
  const float* gWhh   = (const float*)d_in[18];
  const float* gbih   = (const float*)d_in[19];
  const float* gbhh   = (const float*)d_in[20];
  const float* decW   = (const float*)d_in[21];
  const float* decb   = (const float*)d_in[22];
  float* out = (float*)d_out;

  char* wsp = (char*)d_ws;
  auto take = [&](size_t n) { char* p = wsp; wsp += (n + 255) & ~(size_t)255; return p; };

  u16*   wqkvb = (u16*)take((size_t)3072 * 1024 * 2);
  u16*   wob   = (u16*)take((size_t)1024 * 1024 * 2);
  u16*   w1b   = (u16*)take((size_t)4096 * 1024 * 2);
  u16*   w2b   = (u16*)take((size_t)1024 * 4096 * 2);
  float* pe    = (float*)take((size_t)SS * DD * 4);
  float* x32   = (float*)take((size_t)TT * DD * 4);
  u16*   xb    = (u16*)take((size_t)TT * DD * 2);
  u16*   big   = (u16*)take((size_t)TT * FFN * 2);
  u16*   ob    = (u16*)take((size_t)TT * DD * 2);
  u16*   tmp16 = (u16*)take((size_t)TT * DD * 2);
  float* emo   = (float*)take((size_t)BB * SS * GHH * 4);
  float* md    = (float*)take((size_t)BB * NCC * 4);

  (void)hipFuncSetAttribute((const void*)&k_gemm256<0>,
      hipFuncAttributeMaxDynamicSharedMemorySize, 131072);
  (void)hipFuncSetAttribute((const void*)&k_gemm256<1>,
      hipFuncAttributeMaxDynamicSharedMemorySize, 131072);

  // GRU path (fused input projection + scan)
  k_gru<<<BB, 256, 0, stream>>>(em_seq, gWih, gbih, gWhh, gbhh, emo);

  // embedding + positional encoding
  k_pe<<<(SS * DD / 2 + 255) / 256, 256, 0, stream>>>(pe);
  k_embed<<<TT * DD / 4 / 256, 256, 0, stream>>>(src, emb, pe, x32, xb);

  for (int l = 0; l < LL; ++l) {
    k_f2bf4<<<2048, 256, 0, stream>>>(
        Wqkv + (size_t)l * 3072 * 1024, wqkvb, 3072 * 1024 / 4,
        Wo   + (size_t)l * 1024 * 1024, wob,   1024 * 1024 / 4,
        W1   + (size_t)l * 4096 * 1024, w1b,   4096 * 1024 / 4,
        W2   + (size_t)l * 1024 * 4096, w2b,   1024 * 4096 / 4);

    // QKV projection
    k_gemm256<0><<<(TT/256) * (3072/256), 512, 131072, stream>>>(
        xb, wqkvb, bqkv + (size_t)l * 3072, big, TT, 3072, 1024);
    // attention
    k_attn<<<dim3(HH, BB), 256, 0, stream>>>(big, ob);
    // output projection
    k_gemm256<0><<<(TT/256) * (1024/256), 512, 131072, stream>>>(
        ob, wob, bo + (size_t)l * 1024, tmp16, TT, 1024, 1024);
    // residual + LN1
    k_ln<<<TT, 256, 0, stream>>>(x32, tmp16, ln1g + (size_t)l * DD, ln1b + (size_t)l * DD, x32, xb);
    // FFN1 (relu)
    k_gemm256<1><<<(TT/256) * (4096/256), 512, 131072, stream>>>(
        xb, w1b, b1 + (size_t)l * 4096, big, TT, 4096, 1024);
    // FFN2
    k_gemm256<0><<<(TT/256) * (1024/256), 512, 131072, stream>>>(
        big, w2b, b2 + (size_t)l * 1024, tmp16, TT, 1024, 4096);
    // residual + LN2
    k_ln<<<TT, 256, 0, stream>>>(x32, tmp16, ln2g + (size_t)l * DD, ln2b + (size_t)l * DD, x32, xb);
  }

  // decoder
  k_main<<<BB, 64, 0, stream>>>(d_ids, ut_len, x32, decW, md);
  k_dec<<<TT / 4, 256, 0, stream>>>(x32, emo, md, decW, decb, d_ids, ut_len, out);
}

// Round 4
// 2469.344 us; speedup vs baseline: 1.4701x; 1.0257x over previous
//
#include <hip/hip_runtime.h>
#include <hip/hip_bf16.h>
#include <math.h>

// Problem constants
#define BB 64
#define SS 256
#define DD 1024
#define HH 16
#define FFN 4096
#define GHH 100
#define NCC 7
#define LL 4
#define TT (BB*SS)          // 16384 tokens
#define DHH 64

typedef unsigned short u16;
typedef unsigned int u32;
typedef __attribute__((ext_vector_type(4))) float f32x4;
typedef __attribute__((ext_vector_type(8))) short s16x8;
typedef __attribute__((ext_vector_type(4))) unsigned short u16x4;

__device__ __forceinline__ u16 f2bf(float f) {
  union { float f; u32 u; } x; x.f = f;
  u32 r = x.u + 0x7FFFu + ((x.u >> 16) & 1u);
  return (u16)(r >> 16);
}
__device__ __forceinline__ float bf2f(u16 b) {
  union { u32 u; float f; } x; x.u = ((u32)b) << 16;
  return x.f;
}

// ---------------- fused fp32 -> bf16 convert (4 tensors) ----------------
__global__ void k_f2bf4(const float* __restrict__ s0, u16* __restrict__ d0, int n0,
                        const float* __restrict__ s1, u16* __restrict__ d1, int n1,
                        const float* __restrict__ s2, u16* __restrict__ d2, int n2,
                        const float* __restrict__ s3, u16* __restrict__ d3, int n3) {
  int stride = gridDim.x * blockDim.x;
  int total = n0 + n1 + n2 + n3;
  for (int i = blockIdx.x * blockDim.x + threadIdx.x; i < total; i += stride) {
    const float* s; u16* d; int j = i;
    if (j < n0) { s = s0; d = d0; }
    else {
      j -= n0;
      if (j < n1) { s = s1; d = d1; }
      else {
        j -= n1;
        if (j < n2) { s = s2; d = d2; }
        else { j -= n2; s = s3; d = d3; }
      }
    }
    f32x4 v = *(const f32x4*)(s + (size_t)j * 4);
    u16x4 o;
    o[0] = f2bf(v[0]); o[1] = f2bf(v[1]); o[2] = f2bf(v[2]); o[3] = f2bf(v[3]);
    *(u16x4*)(d + (size_t)j * 4) = o;
  }
}

// ---------------- positional encoding ----------------
__global__ void k_pe(float* __restrict__ pe) {
  int i = blockIdx.x * blockDim.x + threadIdx.x;     // over S*D/2
  if (i >= SS * DD / 2) return;
  int s = i / (DD / 2), j = i % (DD / 2);
  float div = __expf((float)(2 * j) * (-9.210340371976184f / (float)DD));
  float a = (float)s * div;
  pe[s * DD + 2 * j]     = sinf(a);
  pe[s * DD + 2 * j + 1] = cosf(a);
}

// ---------------- embedding + PE ----------------
__global__ void k_embed(const int* __restrict__ src, const float* __restrict__ emb,
                        const float* __restrict__ pe, float* __restrict__ x32,
                        u16* __restrict__ xb) {
  int i = blockIdx.x * blockDim.x + threadIdx.x;     // over T*D/4
  if (i >= TT * DD / 4) return;
  int t = i / (DD / 4);
  int d4 = (i % (DD / 4)) * 4;
  int s = t % SS;
  int tok = src[t];
  f32x4 e = *(const f32x4*)(emb + (size_t)tok * DD + d4);
  f32x4 p = *(const f32x4*)(pe + (size_t)s * DD + d4);
  f32x4 r;
  r[0] = e[0] * 32.0f + p[0]; r[1] = e[1] * 32.0f + p[1];
  r[2] = e[2] * 32.0f + p[2]; r[3] = e[3] * 32.0f + p[3];
  *(f32x4*)(x32 + (size_t)t * DD + d4) = r;
  u16x4 o;
  o[0] = f2bf(r[0]); o[1] = f2bf(r[1]); o[2] = f2bf(r[2]); o[3] = f2bf(r[3]);
  *(u16x4*)(xb + (size_t)t * DD + d4) = o;
}

// ---------------- 256x256 8-phase GEMM (T1+T2+T3+T4+T5) ----------------
#define MEMF asm volatile("" ::: "memory")
#define GBAR do { MEMF; __builtin_amdgcn_sched_barrier(0); __builtin_amdgcn_s_barrier(); __builtin_amdgcn_sched_barrier(0); MEMF; } while(0)
#define VMW4 asm volatile("s_waitcnt vmcnt(4)" ::: "memory")

#define STG(P, isB, h, l, buf, kt) \
  __builtin_amdgcn_global_load_lds( \
    (const __attribute__((address_space(1))) u32*)(P[h][l] + (kt)), \
    (__attribute__((address_space(3))) u32*)(smem + (buf)*65536 + (isB)*32768 + (h)*16384 + (l)*8192 + wid*1024), \
    16, 0, 0)

#define LDB(buf) do { \
  _Pragma("unroll") for (int nf = 0; nf < 4; nf++) \
  _Pragma("unroll") for (int kk = 0; kk < 2; kk++) { \
    int rel = (wn*64 + nf*16 + lm)*128 + kk*64 + lg*16; \
    bq[nf][kk] = *(const s16x8*)(smem + (buf)*65536 + 32768 + (rel ^ (((rel>>9)&1)<<5))); \
  } } while(0)

#define LDA(buf, q) do { \
  _Pragma("unroll") for (int ml = 0; ml < 2; ml++) \
  _Pragma("unroll") for (int kk = 0; kk < 2; kk++) { \
    int rel = (wm*128 + ((q)*2+ml)*16 + lm)*128 + kk*64 + lg*16; \
    aq[ml][kk] = *(const s16x8*)(smem + (buf)*65536 + (rel ^ (((rel>>9)&1)<<5))); \
  } } while(0)

#define MFMAQ(q) do { \
  __builtin_amdgcn_s_setprio(1); \
  _Pragma("unroll") for (int ml = 0; ml < 2; ml++) \
  _Pragma("unroll") for (int nf = 0; nf < 4; nf++) \
  _Pragma("unroll") for (int kk = 0; kk < 2; kk++) \
    acc[(q)*2+ml][nf] = __builtin_amdgcn_mfma_f32_16x16x32_bf16(aq[ml][kk], bq[nf][kk], acc[(q)*2+ml][nf], 0, 0, 0); \
  __builtin_amdgcn_s_setprio(0); \
} while(0)

template<int EPI>
__global__ __launch_bounds__(512, 2)
void k_gemm256(const u16* __restrict__ A, const u16* __restrict__ W,
               const float* __restrict__ bias, u16* __restrict__ C,
               int M, int N, int K) {
  extern __shared__ char smem[];
  const int tid = threadIdx.x;
  const int lane = tid & 63;
  const int wid = tid >> 6;
  const int lm = lane & 15, lg = lane >> 4;
  const int wm = wid >> 2, wn = wid & 3;

  const int NB = N >> 8;
  const int nwg = gridDim.x;
  const int bid = blockIdx.x;
  const int cpx = nwg >> 3;
  const int swzb = (bid & 7) * cpx + (bid >> 3);
  const int m0 = (swzb / NB) << 8;
  const int n0 = (swzb % NB) << 8;

  const u16* pA[2][2];
  const u16* pB[2][2];
#pragma unroll
  for (int h = 0; h < 2; h++)
#pragma unroll
    for (int l = 0; l < 2; l++) {
      int rel = h * 16384 + l * 8192 + tid * 16;
      int sb = rel ^ (((rel >> 9) & 1) << 5);
      int grow = sb >> 7;
      int gcol = (sb & 127) >> 1;
      pA[h][l] = A + (size_t)(m0 + grow) * K + gcol;
      pB[h][l] = W + (size_t)(n0 + grow) * K + gcol;
    }

  f32x4 acc[8][4];
#pragma unroll
  for (int i = 0; i < 8; i++)
#pragma unroll
    for (int j = 0; j < 4; j++) acc[i][j] = (f32x4){0.f, 0.f, 0.f, 0.f};

  s16x8 bq[4][2];
  s16x8 aq[2][2];

  const int NT = K >> 6;

  STG(pB,1,0,0,0,0); STG(pB,1,0,1,0,0); STG(pB,1,1,0,0,0); STG(pB,1,1,1,0,0);
  STG(pA,0,0,0,0,0); STG(pA,0,0,1,0,0); STG(pA,0,1,0,0,0); STG(pA,0,1,1,0,0);
  STG(pB,1,0,0,1,64); STG(pB,1,0,1,1,64); STG(pB,1,1,0,1,64); STG(pB,1,1,1,1,64);
  VMW4;
  GBAR;

  for (int i = 0; i < (NT >> 1); i++) {
    const int t1k = (2*i + 1) * 64;
    int t2 = 2*i + 2; if (t2 >= NT) t2 -= NT;
    int t3 = 2*i + 3; if (t3 >= NT) t3 -= NT;
    const int t2k = t2 * 64, t3k = t3 * 64;

    LDB(0); LDA(0,0);
    STG(pA,0,0,0,1,t1k); STG(pA,0,0,1,1,t1k);
    GBAR; MFMAQ(0); GBAR;
    LDA(0,1);
    STG(pA,0,1,0,1,t1k); STG(pA,0,1,1,1,t1k);
    STG(pB,1,0,0,0,t2k); STG(pB,1,0,1,0,t2k);
    GBAR; MFMAQ(1); GBAR;
    LDA(0,2);
    STG(pB,1,1,0,0,t2k); STG(pB,1,1,1,0,t2k);
    GBAR; MFMAQ(2); GBAR;
    LDA(0,3);
    GBAR; MFMAQ(3); VMW4; GBAR;
    LDB(1); LDA(1,0);
    STG(pA,0,0,0,0,t2k); STG(pA,0,0,1,0,t2k);
    GBAR; MFMAQ(0); GBAR;
    LDA(1,1);
    STG(pA,0,1,0,0,t2k); STG(pA,0,1,1,0,t2k);
    GBAR; MFMAQ(1); GBAR;
    LDA(1,2);
    STG(pB,1,0,0,1,t3k); STG(pB,1,0,1,1,t3k);
    GBAR; MFMAQ(2); GBAR;
    LDA(1,3);
    STG(pB,1,1,0,1,t3k); STG(pB,1,1,1,1,t3k);
    GBAR; MFMAQ(3); VMW4; GBAR;
  }

  float bn[4];
#pragma unroll
  for (int nf = 0; nf < 4; nf++) bn[nf] = bias[n0 + wn*64 + nf*16 + lm];
#pragma unroll
  for (int mf = 0; mf < 8; mf++)
#pragma unroll
    for (int nf = 0; nf < 4; nf++) {
      int col = n0 + wn*64 + nf*16 + lm;
#pragma unroll
      for (int r = 0; r < 4; r++) {
        int row = m0 + wm*128 + mf*16 + lg*4 + r;
        float v = acc[mf][nf][r] + bn[nf];
        if (EPI == 1) v = fmaxf(v, 0.f);
        C[(size_t)row * N + col] = f2bf(v);
      }
    }
}

// ---------------- fused causal attention: block=(h,b), wave=q-block ----------
__global__ __launch_bounds__(256, 2)
void k_attn(const u16* __restrict__ qkv, u16* __restrict__ o) {
  const int h = blockIdx.x;     // 0..15
  const int b = blockIdx.y;     // 0..63
  const int lane = threadIdx.x & 63;
  const int w = threadIdx.x >> 6;    // q-block 0..3 (64 rows each)
  const int lm = lane & 15, lg = lane >> 4;

  __shared__ u16 Ks[64 * 64];       // [k_local][dh]
  __shared__ u16 Vt[64 * 64];       // [dh][k_local]
  __shared__ u16 Ps[4][64 * 64];    // per-wave P [q_local][k_local]

  const size_t tokbase = (size_t)b * SS;

  s16x8 aq[4][2];
#pragma unroll
  for (int mf = 0; mf < 4; mf++) {
    const u16* qrow = qkv + (tokbase + w * 64 + mf * 16 + lm) * 3072 + h * 64;
#pragma unroll
    for (int kk = 0; kk < 2; kk++)
      aq[mf][kk] = *(const s16x8*)(qrow + kk * 32 + lg * 8);
  }

  f32x4 zero = {0.f, 0.f, 0.f, 0.f};
  f32x4 oacc[4][4];
#pragma unroll
  for (int mf = 0; mf < 4; mf++)
#pragma unroll
    for (int df = 0; df < 4; df++) oacc[mf][df] = zero;
  float m_run[16], l_run[16];
#pragma unroll
  for (int r = 0; r < 16; r++) { m_run[r] = -3e38f; l_run[r] = 0.f; }

  for (int kb = 0; kb < 4; kb++) {
    __syncthreads();
    {
      int krow = threadIdx.x >> 2;
      int seg  = (threadIdx.x & 3) * 16;
      const u16* ksrc = qkv + (tokbase + kb * 64 + krow) * 3072 + 1024 + h * 64 + seg;
      s16x8 v0 = *(const s16x8*)(ksrc);
      s16x8 v1 = *(const s16x8*)(ksrc + 8);
      *(s16x8*)&Ks[krow * 64 + seg] = v0;
      *(s16x8*)&Ks[krow * 64 + seg + 8] = v1;
      const u16* vsrc = qkv + (tokbase + kb * 64 + krow) * 3072 + 2048 + h * 64 + seg;
      s16x8 w0 = *(const s16x8*)(vsrc);
      s16x8 w1 = *(const s16x8*)(vsrc + 8);
#pragma unroll
      for (int e = 0; e < 8; e++) {
        Vt[(seg + e) * 64 + krow]     = (u16)w0[e];
        Vt[(seg + 8 + e) * 64 + krow] = (u16)w1[e];
      }
    }
    __syncthreads();
    if (w < kb) continue;

    s16x8 bk[4][2];
#pragma unroll
    for (int nf = 0; nf < 4; nf++)
#pragma unroll
      for (int kk = 0; kk < 2; kk++)
        bk[nf][kk] = *(const s16x8*)&Ks[(nf * 16 + lm) * 64 + kk * 32 + lg * 8];

    const int colbase = kb * 64;
#pragma unroll
    for (int mf = 0; mf < 4; mf++) {
      f32x4 sfr[4];
#pragma unroll
      for (int nf = 0; nf < 4; nf++) {
        f32x4 acc = zero;
#pragma unroll
        for (int kk = 0; kk < 2; kk++)
          acc = __builtin_amdgcn_mfma_f32_16x16x32_bf16(aq[mf][kk], bk[nf][kk], acc, 0, 0, 0);
        sfr[nf] = acc;
      }
      const int rowbase = w * 64 + mf * 16 + lg * 4;
#pragma unroll
      for (int nf = 0; nf < 4; nf++) {
        int col = colbase + nf * 16 + lm;
#pragma unroll
        for (int r = 0; r < 4; r++) {
          float v = sfr[nf][r] * 0.125f;
          sfr[nf][r] = (col <= rowbase + r) ? v : -1e30f;
        }
      }
#pragma unroll
      for (int r = 0; r < 4; r++) {
        float m = fmaxf(fmaxf(sfr[0][r], sfr[1][r]), fmaxf(sfr[2][r], sfr[3][r]));
#pragma unroll
        for (int off = 1; off < 16; off <<= 1) m = fmaxf(m, __shfl_xor(m, off));
        int idx = mf * 4 + r;
        float mnew = fmaxf(m_run[idx], m);
        float fo = __expf(m_run[idx] - mnew);
        m_run[idx] = mnew;
        float ps = 0.f;
#pragma unroll
        for (int nf = 0; nf < 4; nf++) {
          float p = __expf(sfr[nf][r] - mnew);
          sfr[nf][r] = p;
          ps += p;
        }
#pragma unroll
        for (int off = 1; off < 16; off <<= 1) ps += __shfl_xor(ps, off);
        l_run[idx] = l_run[idx] * fo + ps;
#pragma unroll
        for (int df = 0; df < 4; df++) oacc[mf][df][r] *= fo;
      }
#pragma unroll
      for (int nf = 0; nf < 4; nf++)
#pragma unroll
        for (int r = 0; r < 4; r++)
          Ps[w][(mf * 16 + lg * 4 + r) * 64 + nf * 16 + lm] = f2bf(sfr[nf][r]);
    }
    asm volatile("" ::: "memory");
    s16x8 bv[4][2];
#pragma unroll
    for (int df = 0; df < 4; df++)
#pragma unroll
      for (int kk = 0; kk < 2; kk++)
        bv[df][kk] = *(const s16x8*)&Vt[(df * 16 + lm) * 64 + kk * 32 + lg * 8];
#pragma unroll
    for (int mf = 0; mf < 4; mf++) {
      s16x8 pa[2];
#pragma unroll
      for (int kk = 0; kk < 2; kk++)
        pa[kk] = *(const s16x8*)&Ps[w][(mf * 16 + lm) * 64 + kk * 32 + lg * 8];
#pragma unroll
      for (int df = 0; df < 4; df++)
#pragma unroll
        for (int kk = 0; kk < 2; kk++)
          oacc[mf][df] = __builtin_amdgcn_mfma_f32_16x16x32_bf16(pa[kk], bv[df][kk], oacc[mf][df], 0, 0, 0);
    }
  }

#pragma unroll
  for (int mf = 0; mf < 4; mf++)
#pragma unroll
    for (int df = 0; df < 4; df++)
#pragma unroll
      for (int r = 0; r < 4; r++) {
        int row = w * 64 + mf * 16 + lg * 4 + r;
        float val = oacc[mf][df][r] / l_run[mf * 4 + r];
        o[(tokbase + row) * 1024 + h * 64 + df * 16 + lm] = f2bf(val);
      }
}

// ---------------- residual + LayerNorm (tmp is bf16) ----------------
__global__ __launch_bounds__(256)
void k_ln(const float* __restrict__ xin, const u16* __restrict__ tmp,
          const float* __restrict__ gam, const float* __restrict__ bet,
          float* __restrict__ xout, u16* __restrict__ xb) {
  int t = blockIdx.x;
  int tid = threadIdx.x;
  f32x4 v = *(const f32x4*)(xin + (size_t)t * DD + tid * 4);
  u16x4 u4 = *(const u16x4*)(tmp + (size_t)t * DD + tid * 4);
  v[0] += bf2f(u4[0]); v[1] += bf2f(u4[1]); v[2] += bf2f(u4[2]); v[3] += bf2f(u4[3]);
  float s = v[0] + v[1] + v[2] + v[3];
  float s2 = v[0]*v[0] + v[1]*v[1] + v[2]*v[2] + v[3]*v[3];
#pragma unroll
  for (int off = 32; off >= 1; off >>= 1) {
    s  += __shfl_xor(s, off);
    s2 += __shfl_xor(s2, off);
  }
  __shared__ float red[8];
  int w = tid >> 6;
  if ((tid & 63) == 0) { red[w] = s; red[4 + w] = s2; }
  __syncthreads();
  s  = red[0] + red[1] + red[2] + red[3];
  s2 = red[4] + red[5] + red[6] + red[7];
  float mean = s * (1.f / 1024.f);
  float var = s2 * (1.f / 1024.f) - mean * mean;
  float rstd = rsqrtf(var + 1e-5f);
  f32x4 g4 = *(const f32x4*)(gam + tid * 4);
  f32x4 b4 = *(const f32x4*)(bet + tid * 4);
  f32x4 y;
  u16x4 yo;
#pragma unroll
  for (int e = 0; e < 4; e++) {
    y[e] = (v[e] - mean) * rstd * g4[e] + b4[e];
    yo[e] = f2bf(y[e]);
  }
  *(f32x4*)(xout + (size_t)t * DD + tid * 4) = y;
  *(u16x4*)(xb + (size_t)t * DD + tid * 4) = yo;
}

// ---------------- GRU: weights in ext-vector REGISTERS (static-indexed) -----
// pair (i, half): half covers k in [half*50, half*50+50); 1 barrier/step.
// f32x4 arrays with fully-unrolled static indices stay in VGPRs (rule r286);
// plain float arrays of this size get alloca'd to scratch (R1-R3 failures).
__global__ __launch_bounds__(256, 1)
void k_gru(const float* __restrict__ em, const float* __restrict__ Wih,
           const float* __restrict__ bih, const float* __restrict__ Whh,
           const float* __restrict__ bhh, float* __restrict__ emo) {
  const int b = blockIdx.x;
  const int tid = threadIdx.x;
  const int iraw = tid >> 1;
  const int i = iraw < 100 ? iraw : 99;    // clamped for safe addresses
  const bool act = iraw < 100;
  const int half = tid & 1;
  __shared__ __align__(16) float h[2][104]; // unit j at slot j + (j>=50 ? 2 : 0)

  f32x4 wr[13], wz[13], wn[13];
#pragma unroll
  for (int q = 0; q < 13; q++) {
#pragma unroll
    for (int e4 = 0; e4 < 4; e4++) {
      int k = q * 4 + e4;                   // compile-time constant
      int kk = half * 50 + (k < 50 ? k : 0);
      float vr = Whh[(size_t)i * 100 + kk];
      float vz = Whh[(size_t)(100 + i) * 100 + kk];
      float vn = Whh[(size_t)(200 + i) * 100 + kk];
      wr[q][e4] = (k < 50) ? vr : 0.f;
      wz[q][e4] = (k < 50) ? vz : 0.f;
      wn[q][e4] = (k < 50) ? vn : 0.f;
    }
  }
  float wir[7], wiz[7], win[7];
#pragma unroll
  for (int f = 0; f < 7; f++) {
    wir[f] = Wih[i * 7 + f];
    wiz[f] = Wih[(100 + i) * 7 + f];
    win[f] = Wih[(200 + i) * 7 + f];
  }
  const float br = bhh[i], bz = bhh[100 + i], bn = bhh[200 + i];
  const float xbr = bih[i], xbz = bih[100 + i], xbn = bih[200 + i];

  if (tid < 104) { h[0][tid] = 0.f; h[1][tid] = 0.f; }
  __syncthreads();

  const float* eb = em + (size_t)b * SS * 7;
  float e[7];
#pragma unroll
  for (int f = 0; f < 7; f++) e[f] = eb[f];

  for (int s = 0; s < SS; ++s) {
    const int cur = s & 1, nxt = cur ^ 1;
    // input projection (used by half==0 lanes in the gate phase)
    float sr = xbr, sz = xbz, sn = xbn;
#pragma unroll
    for (int f = 0; f < 7; f++) {
      sr += wir[f] * e[f]; sz += wiz[f] * e[f]; sn += win[f] * e[f];
    }
    // prefetch next step's em row
    {
      int sp = (s + 1 < SS) ? s + 1 : s;
#pragma unroll
      for (int f = 0; f < 7; f++) e[f] = eb[sp * 7 + f];
    }
    // matvec: vector FMAs against register weights; h via uniform broadcast
    const float* hb = &h[cur][half * 52];
    f32x4 ac_r = {0.f,0.f,0.f,0.f}, ac_z = {0.f,0.f,0.f,0.f}, ac_n = {0.f,0.f,0.f,0.f};
#pragma unroll
    for (int q = 0; q < 13; q++) {
      f32x4 hv = *(const f32x4*)(hb + q * 4);
      ac_r += wr[q] * hv;
      ac_z += wz[q] * hv;
      ac_n += wn[q] * hv;
    }
    float ar = (ac_r[0] + ac_r[1]) + (ac_r[2] + ac_r[3]);
    float az = (ac_z[0] + ac_z[1]) + (ac_z[2] + ac_z[3]);
    float an = (ac_n[0] + ac_n[1]) + (ac_n[2] + ac_n[3]);
    ar += __shfl_xor(ar, 1);
    az += __shfl_xor(az, 1);
    an += __shfl_xor(an, 1);
    if (act && half == 0) {
      int slot = i + (i >= 50 ? 2 : 0);
      float hold = h[cur][slot];
      float rr = 1.f / (1.f + __expf(-(sr + ar + br)));
      float zz = 1.f / (1.f + __expf(-(sz + az + bz)));
      float nx = sn + rr * (an + bn);
      float e2 = __expf(-2.f * fabsf(nx));
      float th = (1.f - e2) / (1.f + e2);
      float nn = copysignf(th, nx);
      float hn = (1.f - zz) * nn + zz * hold;
      h[nxt][slot] = hn;
      emo[((size_t)b * SS + s) * GHH + i] = hn;
    }
    __syncthreads();
  }
}

// ---------------- main-token dot precompute ----------------
__global__ void k_main(const int* __restrict__ d_ids, const int* __restrict__ ut_len,
                       const float* __restrict__ x32, const float* __restrict__ decW,
                       float* __restrict__ md) {
  int b = blockIdx.x;
  int lane = threadIdx.x;   // 64
  int len = ut_len[d_ids[b]];
  const float* xr = x32 + ((size_t)b * SS + (len - 1)) * DD;
  float acc[NCC];
#pragma unroll
  for (int c = 0; c < NCC; c++) acc[c] = 0.f;
  for (int d = lane; d < DD; d += 64) {
    float xv = xr[d];
#pragma unroll
    for (int c = 0; c < NCC; c++) acc[c] += xv * decW[(size_t)c * 2148 + 1024 + d];
  }
#pragma unroll
  for (int c = 0; c < NCC; c++) {
#pragma unroll
    for (int off = 32; off >= 1; off >>= 1) acc[c] += __shfl_xor(acc[c], off);
  }
  if (lane == 0) {
#pragma unroll
    for (int c = 0; c < NCC; c++) md[b * NCC + c] = acc[c];
  }
}

// ---------------- decoder ----------------
__global__ __launch_bounds__(256)
void k_dec(const float* __restrict__ x32, const float* __restrict__ emo,
           const float* __restrict__ md, const float* __restrict__ decW,
           const float* __restrict__ decb, const int* __restrict__ d_ids,
           const int* __restrict__ ut_len, float* __restrict__ out) {
  int grp = threadIdx.x >> 6, lane = threadIdx.x & 63;
  int t = blockIdx.x * 4 + grp;
  int b = t / SS, s = t % SS;
  int len = ut_len[d_ids[b]];
  bool valid = s < len;
  float acc[NCC];
#pragma unroll
  for (int c = 0; c < NCC; c++) acc[c] = 0.f;
  if (valid) {
    const float* xr = x32 + (size_t)t * DD;
    for (int d = lane; d < DD; d += 64) {
      float xv = xr[d];
#pragma unroll
      for (int c = 0; c < NCC; c++) acc[c] += xv * decW[(size_t)c * 2148 + d];
    }
  }
  {
    const float* er = emo + (size_t)t * GHH;
    for (int d = lane; d < GHH; d += 64) {
      float ev = er[d];
#pragma unroll
      for (int c = 0; c < NCC; c++) acc[c] += ev * decW[(size_t)c * 2148 + 2048 + d];
    }
  }
#pragma unroll
  for (int c = 0; c < NCC; c++) {
#pragma unroll
    for (int off = 32; off >= 1; off >>= 1) acc[c] += __shfl_xor(acc[c], off);
  }
  if (lane == 0) {
#pragma unroll
    for (int c = 0; c < NCC; c++) {
      float v = acc[c] + (valid ? md[b * NCC + c] : 0.f) + decb[c];
      out[(size_t)t * NCC + c] = v;
    }
  }
}

// ---------------- launch ----------------
extern "C" void kernel_launch(void* const* d_in, const int* in_sizes, int n_in,
                              void* d_out, int out_size, void* d_ws, size_t ws_size,
                              hipStream_t stream) {
  const int*   src    = (const int*)d_in[0];
  const float* em_seq = (const float*)d_in[1];
  const int*   d_ids  = (const int*)d_in[2];
  const int*   ut_len = (const int*)d_in[3];
  const float* emb    = (const float*)d_in[4];
  const float* Wqkv   = (const float*)d_in[5];
  const float* bqkv   = (const float*)d_in[6];
  const float* Wo     = (const float*)d_in[7];
  const float* bo     = (const float*)d_in[8];
  const float* W1     = (const float*)d_in[9];
  const float* b1     = (const float*)d_in[10];
  const float* W2     = (const float*)d_in[11];
  const float* b2     = (const float*)d_in[12];
  const float* ln1g   = (const float*)d_in[13];
  const float* ln1b   = (const float*)d_in[14];
  const float* ln2g   = (const float*)d_in[15];
  const float* ln2b   = (const float*)d_in[16];
  const float* gWih   = (const float*)d_in[17];
  const float* gWhh   = (const float*)d_in[18];
  const float* gbih   = (const float*)d_in[19];
  const float* gbhh   = (const float*)d_in[20];
  const float* decW   = (const float*)d_in[21];
  const float* decb   = (const float*)d_in[22];
  float* out = (float*)d_out;

  char* wsp = (char*)d_ws;
  auto take = [&](size_t n) { char* p = wsp; wsp += (n + 255) & ~(size_t)255; return p; };

  u16*   wqkvb = (u16*)take((size_t)3072 * 1024 * 2);
  u16*   wob   = (u16*)take((size_t)1024 * 1024 * 2);
  u16*   w1b   = (u16*)take((size_t)4096 * 1024 * 2);
  u16*   w2b   = (u16*)take((size_t)1024 * 4096 * 2);
  float* pe    = (float*)take((size_t)SS * DD * 4);
  float* x32   = (float*)take((size_t)TT * DD * 4);
  u16*   xb    = (u16*)take((size_t)TT * DD * 2);
  u16*   big   = (u16*)take((size_t)TT * FFN * 2);
  u16*   ob    = (u16*)take((size_t)TT * DD * 2);
  u16*   tmp16 = (u16*)take((size_t)TT * DD * 2);
  float* emo   = (float*)take((size_t)BB * SS * GHH * 4);
  float* md    = (float*)take((size_t)BB * NCC * 4);

  (void)hipFuncSetAttribute((const void*)&k_gemm256<0>,
      hipFuncAttributeMaxDynamicSharedMemorySize, 131072);
  (void)hipFuncSetAttribute((const void*)&k_gemm256<1>,
      hipFuncAttributeMaxDynamicSharedMemorySize, 131072);

  // GRU path (fused input projection + scan)
  k_gru<<<BB, 256, 0, stream>>>(em_seq, gWih, gbih, gWhh, gbhh, emo);

  // embedding + positional encoding
  k_pe<<<(SS * DD / 2 + 255) / 256, 256, 0, stream>>>(pe);
  k_embed<<<TT * DD / 4 / 256, 256, 0, stream>>>(src, emb, pe, x32, xb);

  for (int l = 0; l < LL; ++l) {
    k_f2bf4<<<2048, 256, 0, stream>>>(
        Wqkv + (size_t)l * 3072 * 1024, wqkvb, 3072 * 1024 / 4,
        Wo   + (size_t)l * 1024 * 1024, wob,   1024 * 1024 / 4,
        W1   + (size_t)l * 4096 * 1024, w1b,   4096 * 1024 / 4,
        W2   + (size_t)l * 1024 * 4096, w2b,   1024 * 4096 / 4);

    // QKV projection
    k_gemm256<0><<<(TT/256) * (3072/256), 512, 131072, stream>>>(
        xb, wqkvb, bqkv + (size_t)l * 3072, big, TT, 3072, 1024);
    // attention
    k_attn<<<dim3(HH, BB), 256, 0, stream>>>(big, ob);
    // output projection
    k_gemm256<0><<<(TT/256) * (1024/256), 512, 131072, stream>>>(
        ob, wob, bo + (size_t)l * 1024, tmp16, TT, 1024, 1024);
    // residual + LN1
    k_ln<<<TT, 256, 0, stream>>>(x32, tmp16, ln1g + (size_t)l * DD, ln1b + (size_t)l * DD, x32, xb);
    // FFN1 (relu)
    k_gemm256<1><<<(TT/256) * (4096/256), 512, 131072, stream>>>(
        xb, w1b, b1 + (size_t)l * 4096, big, TT, 4096, 1024);
    // FFN2
    k_gemm256<0><<<(TT/256) * (1024/256), 512, 131072, stream>>>(
        big, w2b, b2 + (size_t)l * 1024, tmp16, TT, 1024, 4096);
    // residual + LN2
    k_ln<<<TT, 256, 0, stream>>>(x32, tmp16, ln2g + (size_t)l * DD, ln2b + (size_t)l * DD, x32, xb);
  }

  // decoder
  k_main<<<BB, 64, 0, stream>>>(d_ids, ut_len, x32, decW, md);
  k_dec<<<TT / 4, 256, 0, stream>>>(x32, emo, md, decW, decb, d_ids, ut_len, out);
}

// Round 6
// 2323.520 us; speedup vs baseline: 1.5623x; 1.0628x over previous
//
#include <hip/hip_runtime.h>
#include <hip/hip_bf16.h>
#include <math.h>

// Problem constants
#define BB 64
#define SS 256
#define DD 1024
#define HH 16
#define FFN 4096
#define GHH 100
#define NCC 7
#define LL 4
#define TT (BB*SS)          // 16384 tokens
#define DHH 64

typedef unsigned short u16;
typedef unsigned int u32;
typedef __attribute__((ext_vector_type(4))) float f32x4;
typedef __attribute__((ext_vector_type(8))) short s16x8;
typedef __attribute__((ext_vector_type(4))) unsigned short u16x4;

__device__ __forceinline__ u16 f2bf(float f) {
  union { float f; u32 u; } x; x.f = f;
  u32 r = x.u + 0x7FFFu + ((x.u >> 16) & 1u);
  return (u16)(r >> 16);
}
__device__ __forceinline__ float bf2f(u16 b) {
  union { u32 u; float f; } x; x.u = ((u32)b) << 16;
  return x.f;
}

// ---------------- fused fp32 -> bf16 convert (4 tensors) ----------------
__global__ void k_f2bf4(const float* __restrict__ s0, u16* __restrict__ d0, int n0,
                        const float* __restrict__ s1, u16* __restrict__ d1, int n1,
                        const float* __restrict__ s2, u16* __restrict__ d2, int n2,
                        const float* __restrict__ s3, u16* __restrict__ d3, int n3) {
  int stride = gridDim.x * blockDim.x;
  int total = n0 + n1 + n2 + n3;
  for (int i = blockIdx.x * blockDim.x + threadIdx.x; i < total; i += stride) {
    const float* s; u16* d; int j = i;
    if (j < n0) { s = s0; d = d0; }
    else {
      j -= n0;
      if (j < n1) { s = s1; d = d1; }
      else {
        j -= n1;
        if (j < n2) { s = s2; d = d2; }
        else { j -= n2; s = s3; d = d3; }
      }
    }
    f32x4 v = *(const f32x4*)(s + (size_t)j * 4);
    u16x4 o;
    o[0] = f2bf(v[0]); o[1] = f2bf(v[1]); o[2] = f2bf(v[2]); o[3] = f2bf(v[3]);
    *(u16x4*)(d + (size_t)j * 4) = o;
  }
}

// ---------------- positional encoding ----------------
__global__ void k_pe(float* __restrict__ pe) {
  int i = blockIdx.x * blockDim.x + threadIdx.x;     // over S*D/2
  if (i >= SS * DD / 2) return;
  int s = i / (DD / 2), j = i % (DD / 2);
  float div = __expf((float)(2 * j) * (-9.210340371976184f / (float)DD));
  float a = (float)s * div;
  pe[s * DD + 2 * j]     = sinf(a);
  pe[s * DD + 2 * j + 1] = cosf(a);
}

// ---------------- embedding + PE (single bf16 stream) ----------------
__global__ void k_embed(const int* __restrict__ src, const float* __restrict__ emb,
                        const float* __restrict__ pe, u16* __restrict__ xb) {
  int i = blockIdx.x * blockDim.x + threadIdx.x;     // over T*D/4
  if (i >= TT * DD / 4) return;
  int t = i / (DD / 4);
  int d4 = (i % (DD / 4)) * 4;
  int s = t % SS;
  int tok = src[t];
  f32x4 e = *(const f32x4*)(emb + (size_t)tok * DD + d4);
  f32x4 p = *(const f32x4*)(pe + (size_t)s * DD + d4);
  u16x4 o;
  o[0] = f2bf(e[0] * 32.0f + p[0]); o[1] = f2bf(e[1] * 32.0f + p[1]);
  o[2] = f2bf(e[2] * 32.0f + p[2]); o[3] = f2bf(e[3] * 32.0f + p[3]);
  *(u16x4*)(xb + (size_t)t * DD + d4) = o;
}

// ---------------- 256x256 8-phase GEMM (T1+T2+T3+T4+T5) ----------------
#define MEMF asm volatile("" ::: "memory")
#define GBAR do { MEMF; __builtin_amdgcn_sched_barrier(0); __builtin_amdgcn_s_barrier(); __builtin_amdgcn_sched_barrier(0); MEMF; } while(0)
#define VMW4 asm volatile("s_waitcnt vmcnt(4)" ::: "memory")

#define STG(P, isB, h, l, buf, kt) \
  __builtin_amdgcn_global_load_lds( \
    (const __attribute__((address_space(1))) u32*)(P[h][l] + (kt)), \
    (__attribute__((address_space(3))) u32*)(smem + (buf)*65536 + (isB)*32768 + (h)*16384 + (l)*8192 + wid*1024), \
    16, 0, 0)

#define LDB(buf) do { \
  _Pragma("unroll") for (int nf = 0; nf < 4; nf++) \
  _Pragma("unroll") for (int kk = 0; kk < 2; kk++) { \
    int rel = (wn*64 + nf*16 + lm)*128 + kk*64 + lg*16; \
    bq[nf][kk] = *(const s16x8*)(smem + (buf)*65536 + 32768 + (rel ^ (((rel>>9)&1)<<5))); \
  } } while(0)

#define LDA(buf, q) do { \
  _Pragma("unroll") for (int ml = 0; ml < 2; ml++) \
  _Pragma("unroll") for (int kk = 0; kk < 2; kk++) { \
    int rel = (wm*128 + ((q)*2+ml)*16 + lm)*128 + kk*64 + lg*16; \
    aq[ml][kk] = *(const s16x8*)(smem + (buf)*65536 + (rel ^ (((rel>>9)&1)<<5))); \
  } } while(0)

#define MFMAQ(q) do { \
  __builtin_amdgcn_s_setprio(1); \
  _Pragma("unroll") for (int ml = 0; ml < 2; ml++) \
  _Pragma("unroll") for (int nf = 0; nf < 4; nf++) \
  _Pragma("unroll") for (int kk = 0; kk < 2; kk++) \
    acc[(q)*2+ml][nf] = __builtin_amdgcn_mfma_f32_16x16x32_bf16(aq[ml][kk], bq[nf][kk], acc[(q)*2+ml][nf], 0, 0, 0); \
  __builtin_amdgcn_s_setprio(0); \
} while(0)

template<int EPI>
__global__ __launch_bounds__(512, 2)
void k_gemm256(const u16* __restrict__ A, const u16* __restrict__ W,
               const float* __restrict__ bias, u16* __restrict__ C,
               int M, int N, int K) {
  extern __shared__ char smem[];
  const int tid = threadIdx.x;
  const int lane = tid & 63;
  const int wid = tid >> 6;
  const int lm = lane & 15, lg = lane >> 4;
  const int wm = wid >> 2, wn = wid & 3;

  const int NB = N >> 8;
  const int nwg = gridDim.x;
  const int bid = blockIdx.x;
  const int cpx = nwg >> 3;
  const int swzb = (bid & 7) * cpx + (bid >> 3);
  const int m0 = (swzb / NB) << 8;
  const int n0 = (swzb % NB) << 8;

  const u16* pA[2][2];
  const u16* pB[2][2];
#pragma unroll
  for (int h = 0; h < 2; h++)
#pragma unroll
    for (int l = 0; l < 2; l++) {
      int rel = h * 16384 + l * 8192 + tid * 16;
      int sb = rel ^ (((rel >> 9) & 1) << 5);
      int grow = sb >> 7;
      int gcol = (sb & 127) >> 1;
      pA[h][l] = A + (size_t)(m0 + grow) * K + gcol;
      pB[h][l] = W + (size_t)(n0 + grow) * K + gcol;
    }

  f32x4 acc[8][4];
#pragma unroll
  for (int i = 0; i < 8; i++)
#pragma unroll
    for (int j = 0; j < 4; j++) acc[i][j] = (f32x4){0.f, 0.f, 0.f, 0.f};

  s16x8 bq[4][2];
  s16x8 aq[2][2];

  const int NT = K >> 6;

  STG(pB,1,0,0,0,0); STG(pB,1,0,1,0,0); STG(pB,1,1,0,0,0); STG(pB,1,1,1,0,0);
  STG(pA,0,0,0,0,0); STG(pA,0,0,1,0,0); STG(pA,0,1,0,0,0); STG(pA,0,1,1,0,0);
  STG(pB,1,0,0,1,64); STG(pB,1,0,1,1,64); STG(pB,1,1,0,1,64); STG(pB,1,1,1,1,64);
  VMW4;
  GBAR;

  for (int i = 0; i < (NT >> 1); i++) {
    const int t1k = (2*i + 1) * 64;
    int t2 = 2*i + 2; if (t2 >= NT) t2 -= NT;
    int t3 = 2*i + 3; if (t3 >= NT) t3 -= NT;
    const int t2k = t2 * 64, t3k = t3 * 64;

    LDB(0); LDA(0,0);
    STG(pA,0,0,0,1,t1k); STG(pA,0,0,1,1,t1k);
    GBAR; MFMAQ(0); GBAR;
    LDA(0,1);
    STG(pA,0,1,0,1,t1k); STG(pA,0,1,1,1,t1k);
    STG(pB,1,0,0,0,t2k); STG(pB,1,0,1,0,t2k);
    GBAR; MFMAQ(1); GBAR;
    LDA(0,2);
    STG(pB,1,1,0,0,t2k); STG(pB,1,1,1,0,t2k);
    GBAR; MFMAQ(2); GBAR;
    LDA(0,3);
    GBAR; MFMAQ(3); VMW4; GBAR;
    LDB(1); LDA(1,0);
    STG(pA,0,0,0,0,t2k); STG(pA,0,0,1,0,t2k);
    GBAR; MFMAQ(0); GBAR;
    LDA(1,1);
    STG(pA,0,1,0,0,t2k); STG(pA,0,1,1,0,t2k);
    GBAR; MFMAQ(1); GBAR;
    LDA(1,2);
    STG(pB,1,0,0,1,t3k); STG(pB,1,0,1,1,t3k);
    GBAR; MFMAQ(2); GBAR;
    LDA(1,3);
    STG(pB,1,1,0,1,t3k); STG(pB,1,1,1,1,t3k);
    GBAR; MFMAQ(3); VMW4; GBAR;
  }

  float bn[4];
#pragma unroll
  for (int nf = 0; nf < 4; nf++) bn[nf] = bias[n0 + wn*64 + nf*16 + lm];
#pragma unroll
  for (int mf = 0; mf < 8; mf++)
#pragma unroll
    for (int nf = 0; nf < 4; nf++) {
      int col = n0 + wn*64 + nf*16 + lm;
#pragma unroll
      for (int r = 0; r < 4; r++) {
        int row = m0 + wm*128 + mf*16 + lg*4 + r;
        float v = acc[mf][nf][r] + bn[nf];
        if (EPI == 1) v = fmaxf(v, 0.f);
        C[(size_t)row * N + col] = f2bf(v);
      }
    }
}

// ---------------- fused causal attention: block=(h,b), wave=q-block ----------
__global__ __launch_bounds__(256, 2)
void k_attn(const u16* __restrict__ qkv, u16* __restrict__ o) {
  const int h = blockIdx.x;     // 0..15
  const int b = blockIdx.y;     // 0..63
  const int lane = threadIdx.x & 63;
  const int w = threadIdx.x >> 6;    // q-block 0..3 (64 rows each)
  const int lm = lane & 15, lg = lane >> 4;

  __shared__ u16 Ks[64 * 64];       // [k_local][dh]
  __shared__ u16 Vt[64 * 64];       // [dh][k_local]
  __shared__ u16 Ps[4][64 * 64];    // per-wave P [q_local][k_local]

  const size_t tokbase = (size_t)b * SS;

  s16x8 aq[4][2];
#pragma unroll
  for (int mf = 0; mf < 4; mf++) {
    const u16* qrow = qkv + (tokbase + w * 64 + mf * 16 + lm) * 3072 + h * 64;
#pragma unroll
    for (int kk = 0; kk < 2; kk++)
      aq[mf][kk] = *(const s16x8*)(qrow + kk * 32 + lg * 8);
  }

  f32x4 zero = {0.f, 0.f, 0.f, 0.f};
  f32x4 oacc[4][4];
#pragma unroll
  for (int mf = 0; mf < 4; mf++)
#pragma unroll
    for (int df = 0; df < 4; df++) oacc[mf][df] = zero;
  float m_run[16], l_run[16];
#pragma unroll
  for (int r = 0; r < 16; r++) { m_run[r] = -3e38f; l_run[r] = 0.f; }

  for (int kb = 0; kb < 4; kb++) {
    __syncthreads();
    {
      int krow = threadIdx.x >> 2;
      int seg  = (threadIdx.x & 3) * 16;
      const u16* ksrc = qkv + (tokbase + kb * 64 + krow) * 3072 + 1024 + h * 64 + seg;
      s16x8 v0 = *(const s16x8*)(ksrc);
      s16x8 v1 = *(const s16x8*)(ksrc + 8);
      *(s16x8*)&Ks[krow * 64 + seg] = v0;
      *(s16x8*)&Ks[krow * 64 + seg + 8] = v1;
      const u16* vsrc = qkv + (tokbase + kb * 64 + krow) * 3072 + 2048 + h * 64 + seg;
      s16x8 w0 = *(const s16x8*)(vsrc);
      s16x8 w1 = *(const s16x8*)(vsrc + 8);
#pragma unroll
      for (int e = 0; e < 8; e++) {
        Vt[(seg + e) * 64 + krow]     = (u16)w0[e];
        Vt[(seg + 8 + e) * 64 + krow] = (u16)w1[e];
      }
    }
    __syncthreads();
    if (w < kb) continue;

    s16x8 bk[4][2];
#pragma unroll
    for (int nf = 0; nf < 4; nf++)
#pragma unroll
      for (int kk = 0; kk < 2; kk++)
        bk[nf][kk] = *(const s16x8*)&Ks[(nf * 16 + lm) * 64 + kk * 32 + lg * 8];

    const int colbase = kb * 64;
#pragma unroll
    for (int mf = 0; mf < 4; mf++) {
      f32x4 sfr[4];
#pragma unroll
      for (int nf = 0; nf < 4; nf++) {
        f32x4 acc = zero;
#pragma unroll
        for (int kk = 0; kk < 2; kk++)
          acc = __builtin_amdgcn_mfma_f32_16x16x32_bf16(aq[mf][kk], bk[nf][kk], acc, 0, 0, 0);
        sfr[nf] = acc;
      }
      const int rowbase = w * 64 + mf * 16 + lg * 4;
#pragma unroll
      for (int nf = 0; nf < 4; nf++) {
        int col = colbase + nf * 16 + lm;
#pragma unroll
        for (int r = 0; r < 4; r++) {
          float v = sfr[nf][r] * 0.125f;
          sfr[nf][r] = (col <= rowbase + r) ? v : -1e30f;
        }
      }
#pragma unroll
      for (int r = 0; r < 4; r++) {
        float m = fmaxf(fmaxf(sfr[0][r], sfr[1][r]), fmaxf(sfr[2][r], sfr[3][r]));
#pragma unroll
        for (int off = 1; off < 16; off <<= 1) m = fmaxf(m, __shfl_xor(m, off));
        int idx = mf * 4 + r;
        float mnew = fmaxf(m_run[idx], m);
        float fo = __expf(m_run[idx] - mnew);
        m_run[idx] = mnew;
        float ps = 0.f;
#pragma unroll
        for (int nf = 0; nf < 4; nf++) {
          float p = __expf(sfr[nf][r] - mnew);
          sfr[nf][r] = p;
          ps += p;
        }
#pragma unroll
        for (int off = 1; off < 16; off <<= 1) ps += __shfl_xor(ps, off);
        l_run[idx] = l_run[idx] * fo + ps;
#pragma unroll
        for (int df = 0; df < 4; df++) oacc[mf][df][r] *= fo;
      }
#pragma unroll
      for (int nf = 0; nf < 4; nf++)
#pragma unroll
        for (int r = 0; r < 4; r++)
          Ps[w][(mf * 16 + lg * 4 + r) * 64 + nf * 16 + lm] = f2bf(sfr[nf][r]);
    }
    asm volatile("" ::: "memory");
    s16x8 bv[4][2];
#pragma unroll
    for (int df = 0; df < 4; df++)
#pragma unroll
      for (int kk = 0; kk < 2; kk++)
        bv[df][kk] = *(const s16x8*)&Vt[(df * 16 + lm) * 64 + kk * 32 + lg * 8];
#pragma unroll
    for (int mf = 0; mf < 4; mf++) {
      s16x8 pa[2];
#pragma unroll
      for (int kk = 0; kk < 2; kk++)
        pa[kk] = *(const s16x8*)&Ps[w][(mf * 16 + lm) * 64 + kk * 32 + lg * 8];
#pragma unroll
      for (int df = 0; df < 4; df++)
#pragma unroll
        for (int kk = 0; kk < 2; kk++)
          oacc[mf][df] = __builtin_amdgcn_mfma_f32_16x16x32_bf16(pa[kk], bv[df][kk], oacc[mf][df], 0, 0, 0);
    }
  }

#pragma unroll
  for (int mf = 0; mf < 4; mf++)
#pragma unroll
    for (int df = 0; df < 4; df++)
#pragma unroll
      for (int r = 0; r < 4; r++) {
        int row = w * 64 + mf * 16 + lg * 4 + r;
        float val = oacc[mf][df][r] / l_run[mf * 4 + r];
        o[(tokbase + row) * 1024 + h * 64 + df * 16 + lm] = f2bf(val);
      }
}

// ---------------- residual + LayerNorm, in-place on the bf16 stream --------
// Reference is POST-LN: next residual = LN output. So xb <- LN(xb + tmp).
__global__ __launch_bounds__(256)
void k_ln(u16* __restrict__ xb, const u16* __restrict__ tmp,
          const float* __restrict__ gam, const float* __restrict__ bet) {
  int t = blockIdx.x;
  int tid = threadIdx.x;
  u16x4 a4 = *(const u16x4*)(xb + (size_t)t * DD + tid * 4);
  u16x4 u4 = *(const u16x4*)(tmp + (size_t)t * DD + tid * 4);
  f32x4 v;
#pragma unroll
  for (int e = 0; e < 4; e++) v[e] = bf2f(a4[e]) + bf2f(u4[e]);
  float s = v[0] + v[1] + v[2] + v[3];
  float s2 = v[0]*v[0] + v[1]*v[1] + v[2]*v[2] + v[3]*v[3];
#pragma unroll
  for (int off = 32; off >= 1; off >>= 1) {
    s  += __shfl_xor(s, off);
    s2 += __shfl_xor(s2, off);
  }
  __shared__ float red[8];
  int w = tid >> 6;
  if ((tid & 63) == 0) { red[w] = s; red[4 + w] = s2; }
  __syncthreads();
  s  = red[0] + red[1] + red[2] + red[3];
  s2 = red[4] + red[5] + red[6] + red[7];
  float mean = s * (1.f / 1024.f);
  float var = s2 * (1.f / 1024.f) - mean * mean;
  float rstd = rsqrtf(var + 1e-5f);
  f32x4 g4 = *(const f32x4*)(gam + tid * 4);
  f32x4 b4 = *(const f32x4*)(bet + tid * 4);
  u16x4 yo;
#pragma unroll
  for (int e = 0; e < 4; e++)
    yo[e] = f2bf((v[e] - mean) * rstd * g4[e] + b4[e]);
  *(u16x4*)(xb + (size_t)t * DD + tid * 4) = yo;
}

// ---------------- GRU: NAMED register weights (no allocas at all) ----------
#define QL(X) X(0) X(1) X(2) X(3) X(4) X(5) X(6) X(7) X(8) X(9) X(10) X(11)
#define F7(X) X(0) X(1) X(2) X(3) X(4) X(5) X(6)

__global__ __launch_bounds__(256, 1)
void k_gru(const float* __restrict__ em, const float* __restrict__ Wih,
           const float* __restrict__ bih, const float* __restrict__ Whh,
           const float* __restrict__ bhh, float* __restrict__ emo) {
  const int b = blockIdx.x;
  const int tid = threadIdx.x;
  const int iraw = tid >> 1;
  const int i = iraw < 100 ? iraw : 99;    // clamped for safe addresses
  const bool act = iraw < 100;
  const int half = tid & 1;
  __shared__ __align__(16) float h[2][104]; // unit j at slot j + (j>=50 ? 2 : 0)

  const float* rowR = Whh + (size_t)i * 100 + half * 50;
  const float* rowZ = Whh + (size_t)(100 + i) * 100 + half * 50;
  const float* rowN = Whh + (size_t)(200 + i) * 100 + half * 50;

#define LOADQ(q) \
  f32x4 wr##q = {rowR[4*q], rowR[4*q+1], rowR[4*q+2], rowR[4*q+3]}; \
  f32x4 wz##q = {rowZ[4*q], rowZ[4*q+1], rowZ[4*q+2], rowZ[4*q+3]}; \
  f32x4 wn##q = {rowN[4*q], rowN[4*q+1], rowN[4*q+2], rowN[4*q+3]};
  QL(LOADQ)
#undef LOADQ
  f32x4 wr12 = {rowR[48], rowR[49], 0.f, 0.f};
  f32x4 wz12 = {rowZ[48], rowZ[49], 0.f, 0.f};
  f32x4 wn12 = {rowN[48], rowN[49], 0.f, 0.f};

#define LOADI(f) \
  float wir##f = Wih[i * 7 + f]; \
  float wiz##f = Wih[(100 + i) * 7 + f]; \
  float win##f = Wih[(200 + i) * 7 + f];
  F7(LOADI)
#undef LOADI
  const float br = bhh[i], bz = bhh[100 + i], bn = bhh[200 + i];
  const float xbr = bih[i], xbz = bih[100 + i], xbn = bih[200 + i];

  if (tid < 104) { h[0][tid] = 0.f; h[1][tid] = 0.f; }
  __syncthreads();

  const float* eb = em + (size_t)b * SS * 7;
#define DECLE(f) float e##f = eb[f];
  F7(DECLE)
#undef DECLE

  for (int s = 0; s < SS; ++s) {
    const int cur = s & 1, nxt = cur ^ 1;
    float sr = xbr, sz = xbz, sn = xbn;
#define MACI(f) sr += wir##f * e##f; sz += wiz##f * e##f; sn += win##f * e##f;
    F7(MACI)
#undef MACI
    {
      int sp = (s + 1 < SS) ? s + 1 : s;
#define LDE(f) e##f = eb[sp * 7 + f];
      F7(LDE)
#undef LDE
    }
    const float* hb = &h[cur][half * 52];
    f32x4 ar4 = {0.f,0.f,0.f,0.f}, az4 = {0.f,0.f,0.f,0.f}, an4 = {0.f,0.f,0.f,0.f};
#define MACQ(q) { f32x4 hv = *(const f32x4*)(hb + 4*q); \
    ar4 += wr##q * hv; az4 += wz##q * hv; an4 += wn##q * hv; }
    QL(MACQ) MACQ(12)
#undef MACQ
    float ar = (ar4[0] + ar4[1]) + (ar4[2] + ar4[3]);
    float az = (az4[0] + az4[1]) + (az4[2] + az4[3]);
    float an = (an4[0] + an4[1]) + (an4[2] + an4[3]);
    ar += __shfl_xor(ar, 1);
    az += __shfl_xor(az, 1);
    an += __shfl_xor(an, 1);
    if (act && half == 0) {
      int slot = i + (i >= 50 ? 2 : 0);
      float hold = h[cur][slot];
      float rr = 1.f / (1.f + __expf(-(sr + ar + br)));
      float zz = 1.f / (1.f + __expf(-(sz + az + bz)));
      float nx = sn + rr * (an + bn);
      float e2 = __expf(-2.f * fabsf(nx));
      float th = (1.f - e2) / (1.f + e2);
      float nn = copysignf(th, nx);
      float hn = (1.f - zz) * nn + zz * hold;
      h[nxt][slot] = hn;
      emo[((size_t)b * SS + s) * GHH + i] = hn;
    }
    __syncthreads();
  }
}

// ---------------- main-token dot precompute (x is bf16) ----------------
__global__ void k_main(const int* __restrict__ d_ids, const int* __restrict__ ut_len,
                       const u16* __restrict__ x, const float* __restrict__ decW,
                       float* __restrict__ md) {
  int b = blockIdx.x;
  int lane = threadIdx.x;   // 64
  int len = ut_len[d_ids[b]];
  const u16* xr = x + ((size_t)b * SS + (len - 1)) * DD;
  float acc[NCC];
#pragma unroll
  for (int c = 0; c < NCC; c++) acc[c] = 0.f;
  for (int d = lane; d < DD; d += 64) {
    float xv = bf2f(xr[d]);
#pragma unroll
    for (int c = 0; c < NCC; c++) acc[c] += xv * decW[(size_t)c * 2148 + 1024 + d];
  }
#pragma unroll
  for (int c = 0; c < NCC; c++) {
#pragma unroll
    for (int off = 32; off >= 1; off >>= 1) acc[c] += __shfl_xor(acc[c], off);
  }
  if (lane == 0) {
#pragma unroll
    for (int c = 0; c < NCC; c++) md[b * NCC + c] = acc[c];
  }
}

// ---------------- decoder (x is bf16) ----------------
__global__ __launch_bounds__(256)
void k_dec(const u16* __restrict__ x, const float* __restrict__ emo,
           const float* __restrict__ md, const float* __restrict__ decW,
           const float* __restrict__ decb, const int* __restrict__ d_ids,
           const int* __restrict__ ut_len, float* __restrict__ out) {
  int grp = threadIdx.x >> 6, lane = threadIdx.x & 63;
  int t = blockIdx.x * 4 + grp;
  int b = t / SS, s = t % SS;
  int len = ut_len[d_ids[b]];
  bool valid = s < len;
  float acc[NCC];
#pragma unroll
  for (int c = 0; c < NCC; c++) acc[c] = 0.f;
  if (valid) {
    const u16* xrow = x + (size_t)t * DD;
    for (int d = lane; d < DD; d += 64) {
      float xv = bf2f(xrow[d]);
#pragma unroll
      for (int c = 0; c < NCC; c++) acc[c] += xv * decW[(size_t)c * 2148 + d];
    }
  }
  {
    const float* er = emo + (size_t)t * GHH;
    for (int d = lane; d < GHH; d += 64) {
      float ev = er[d];
#pragma unroll
      for (int c = 0; c < NCC; c++) acc[c] += ev * decW[(size_t)c * 2148 + 2048 + d];
    }
  }
#pragma unroll
  for (int c = 0; c < NCC; c++) {
#pragma unroll
    for (int off = 32; off >= 1; off >>= 1) acc[c] += __shfl_xor(acc[c], off);
  }
  if (lane == 0) {
#pragma unroll
    for (int c = 0; c < NCC; c++) {
      float v = acc[c] + (valid ? md[b * NCC + c] : 0.f) + decb[c];
      out[(size_t)t * NCC + c] = v;
    }
  }
}

// ---------------- launch ----------------
extern "C" void kernel_launch(void* const* d_in, const int* in_sizes, int n_in,
                              void* d_out, int out_size, void* d_ws, size_t ws_size,
                              hipStream_t stream) {
  const int*   src    = (const int*)d_in[0];
  const float* em_seq = (const float*)d_in[1];
  const int*   d_ids  = (const int*)d_in[2];
  const int*   ut_len = (const int*)d_in[3];
  const float* emb    = (const float*)d_in[4];
  const float* Wqkv   = (const float*)d_in[5];
  const float* bqkv   = (const float*)d_in[6];
  const float* Wo     = (const float*)d_in[7];
  const float* bo     = (const float*)d_in[8];
  const float* W1     = (const float*)d_in[9];
  const float* b1     = (const float*)d_in[10];
  const float* W2     = (const float*)d_in[11];
  const float* b2     = (const float*)d_in[12];
  const float* ln1g   = (const float*)d_in[13];
  const float* ln1b   = (const float*)d_in[14];
  const float* ln2g   = (const float*)d_in[15];
  const float* ln2b   = (const float*)d_in[16];
  const float* gWih   = (const float*)d_in[17];
  const float* gWhh   = (const float*)d_in[18];
  const float* gbih   = (const float*)d_in[19];
  const float* gbhh   = (const float*)d_in[20];
  const float* decW   = (const float*)d_in[21];
  const float* decb   = (const float*)d_in[22];
  float* out = (float*)d_out;

  char* wsp = (char*)d_ws;
  auto take = [&](size_t n) { char* p = wsp; wsp += (n + 255) & ~(size_t)255; return p; };

  u16*   wqkvb = (u16*)take((size_t)3072 * 1024 * 2);
  u16*   wob   = (u16*)take((size_t)1024 * 1024 * 2);
  u16*   w1b   = (u16*)take((size_t)4096 * 1024 * 2);
  u16*   w2b   = (u16*)take((size_t)1024 * 4096 * 2);
  float* pe    = (float*)take((size_t)SS * DD * 4);
  u16*   xb    = (u16*)take((size_t)TT * DD * 2);
  u16*   big   = (u16*)take((size_t)TT * FFN * 2);
  u16*   ob    = (u16*)take((size_t)TT * DD * 2);
  u16*   tmp16 = (u16*)take((size_t)TT * DD * 2);
  float* emo   = (float*)take((size_t)BB * SS * GHH * 4);
  float* md    = (float*)take((size_t)BB * NCC * 4);

  (void)hipFuncSetAttribute((const void*)&k_gemm256<0>,
      hipFuncAttributeMaxDynamicSharedMemorySize, 131072);
  (void)hipFuncSetAttribute((const void*)&k_gemm256<1>,
      hipFuncAttributeMaxDynamicSharedMemorySize, 131072);

  // GRU path (fused input projection + scan)
  k_gru<<<BB, 256, 0, stream>>>(em_seq, gWih, gbih, gWhh, gbhh, emo);

  // embedding + positional encoding
  k_pe<<<(SS * DD / 2 + 255) / 256, 256, 0, stream>>>(pe);
  k_embed<<<TT * DD / 4 / 256, 256, 0, stream>>>(src, emb, pe, xb);

  for (int l = 0; l < LL; ++l) {
    k_f2bf4<<<2048, 256, 0, stream>>>(
        Wqkv + (size_t)l * 3072 * 1024, wqkvb, 3072 * 1024 / 4,
        Wo   + (size_t)l * 1024 * 1024, wob,   1024 * 1024 / 4,
        W1   + (size_t)l * 4096 * 1024, w1b,   4096 * 1024 / 4,
        W2   + (size_t)l * 1024 * 4096, w2b,   1024 * 4096 / 4);

    // QKV projection (reads xb = residual/LN stream)
    k_gemm256<0><<<(TT/256) * (3072/256), 512, 131072, stream>>>(
        xb, wqkvb, bqkv + (size_t)l * 3072, big, TT, 3072, 1024);
    // attention
    k_attn<<<dim3(HH, BB), 256, 0, stream>>>(big, ob);
    // output projection
    k_gemm256<0><<<(TT/256) * (1024/256), 512, 131072, stream>>>(
        ob, wob, bo + (size_t)l * 1024, tmp16, TT, 1024, 1024);
    // residual + LN1  (xb <- LN(xb + tmp16))
    k_ln<<<TT, 256, 0, stream>>>(xb, tmp16, ln1g + (size_t)l * DD, ln1b + (size_t)l * DD);
    // FFN1 (relu)
    k_gemm256<1><<<(TT/256) * (4096/256), 512, 131072, stream>>>(
        xb, w1b, b1 + (size_t)l * 4096, big, TT, 4096, 1024);
    // FFN2
    k_gemm256<0><<<(TT/256) * (1024/256), 512, 131072, stream>>>(
        big, w2b, b2 + (size_t)l * 1024, tmp16, TT, 1024, 4096);
    // residual + LN2  (xb <- LN(xb + tmp16))
    k_ln<<<TT, 256, 0, stream>>>(xb, tmp16, ln2g + (size_t)l * DD, ln2b + (size_t)l * DD);
  }

  // decoder
  k_main<<<BB, 64, 0, stream>>>(d_ids, ut_len, xb, decW, md);
  k_dec<<<TT / 4, 256, 0, stream>>>(xb, emo, md, decW, decb, d_ids, ut_len, out);
}